// Round 6
// baseline (1304.277 us; speedup 1.0000x reference)
//
#include <hip/hip_runtime.h>
#include <hip/hip_bf16.h>
#include <hip/hip_cooperative_groups.h>

namespace cg = cooperative_groups;

// Decoder (EGNN) on MI355X. pos==0 identity => stage-2/pos/counts dead.
// Round 6: ONE cooperative kernel (768 blocks = 3/CU, 12 grid syncs) replaces
// 14 short launches — round-5 profile showed every kernel <43us, so launch
// gaps + ramp/drain between serially-dependent short kernels dominate.
// Fallback: if hipLaunchCooperativeKernel errors, run the proven round-5
// multi-kernel path (same ws layout, same math).

namespace {

constexpr int kB = 16, kN = 1024, kH = 64, kE = 32768, kLat = 128;
constexpr int kC = 24;                 // edges per wave-chunk
constexpr int kGrid = 768;             // 3 blocks/CU on 256 CUs

typedef __attribute__((ext_vector_type(8))) short short8;   // 8 bf16
typedef __attribute__((ext_vector_type(4))) float floatx4;

__device__ __forceinline__ unsigned short f2bf(float f){   // RNE
  union { float f; unsigned int u; } v; v.f = f;
  unsigned int r = v.u + 0x7fffu + ((v.u >> 16) & 1u);
  return (unsigned short)(r >> 16);
}
__device__ __forceinline__ unsigned int packbf(float a, float b){
  return ((unsigned int)f2bf(b) << 16) | (unsigned int)f2bf(a);
}
__device__ __forceinline__ unsigned int pack2f(float a, float b){ // fast half-up
  unsigned int ua = __float_as_uint(a) + 0x8000u;
  unsigned int ub = __float_as_uint(b) + 0x8000u;
  return __builtin_amdgcn_perm(ub, ua, 0x07060302);
}
__device__ __forceinline__ float bflo(unsigned int u){
  union { unsigned int u; float f; } v; v.u = u << 16; return v.f;
}
__device__ __forceinline__ float bfhi(unsigned int u){
  union { unsigned int u; float f; } v; v.u = u & 0xffff0000u; return v.f;
}
__device__ __forceinline__ float silu2(float x){   // 2 trans + 3 alu
  float u = __builtin_amdgcn_exp2f(-1.44269504f * x);
  return x * __builtin_amdgcn_rcpf(1.0f + u);
}

struct Params {
  const float *z, *nf, *Wg, *bg, *Wn, *bn, *eW1, *eb1, *eW2, *eb2;
  const float *nW1, *nb1, *nW2, *nb2, *lng, *lnb, *oW1, *ob1, *oW2, *ob2;
  const int *ei;
  float *h, *A1t, *P, *g, *out;
  unsigned short *A2bf, *wfragE;
  int *cntI, *off, *ioff, *fill, *items, *nitems, *ecol;
};

// ============================ THE cooperative kernel ========================
__global__ __launch_bounds__(256, 3) void k_all(Params p){
  __shared__ __align__(16) float W0[4096];
  __shared__ __align__(16) float W1[4096];
  __shared__ __align__(16) float HR[16*68];
  __shared__ __align__(16) float AG[16*68];
  __shared__ float b1s[64], b2s[64], lgs[64], lbs[64];
  __shared__ float W2o[192];
  __shared__ float ob2s[4];

  cg::grid_group gg = cg::this_grid();
  const int tid = threadIdx.x, blk = blockIdx.x;
  const int rl = tid >> 4, cc = tid & 15, j0 = cc*4;
  const int wav = tid >> 6, lane = tid & 63;
  const int m = lane & 15, quad = lane >> 4;

  // ---- P0: degree count + wfrag (blk 0-3) + g GEMM (blk 4) ----------------
  for (int e = blk*256 + tid; e < kE; e += kGrid*256)
    atomicAdd(&p.cntI[p.ei[e]], 1);
  if (blk < 4){
    int l = blk;
    for (int i = tid; i < 4096; i += 256){
      int f = i >> 9, ln = (i >> 3) & 63, j8 = i & 7;
      int jt = f >> 1, ks = f & 1;
      int k = ks*32 + (ln >> 4)*8 + j8;
      int j = jt*16 + (ln & 15);
      p.wfragE[l*4096 + i] = f2bf(p.eW2[l*4096 + k*64 + j]);
    }
  } else if (blk == 4){
    int j = tid & 63, b0 = tid >> 6;
    for (int b = b0; b < 16; b += 4){
      float acc = p.bg[j];
      for (int k = 0; k < kLat; k++) acc += p.z[b*kLat + k] * p.Wg[k*64 + j];
      p.g[b*64 + j] = acc;
    }
  }
  gg.sync();

  // ---- P1: scans + item list (block 0 only) -------------------------------
  if (blk == 0){
    int* s0 = (int*)W0; int* s1 = s0 + 1024;
    for (int i = tid; i < 1024; i += 256) s0[i] = p.cntI[i];
    __syncthreads();
    int* src = s0; int* dst = s1;
    for (int o = 1; o < 1024; o <<= 1){
      for (int i = tid; i < 1024; i += 256)
        dst[i] = src[i] + ((i >= o) ? src[i-o] : 0);
      __syncthreads();
      int* t = src; src = dst; dst = t;
    }
    for (int i = tid; i < 1024; i += 256){
      int c = p.cntI[i];
      p.off[i] = c ? (src[i] - c) : src[i];  // exclusive (c==0 same value)
      p.off[i] = src[i] - c;
      p.fill[i] = 0;
    }
    if (tid == 0) p.off[1024] = src[1023];
    __syncthreads();
    for (int i = tid; i < 1024; i += 256) dst[i] = (p.cntI[i] + kC - 1)/kC;
    __syncthreads();
    int* src2 = dst; int* dst2 = src;
    for (int o = 1; o < 1024; o <<= 1){
      for (int i = tid; i < 1024; i += 256)
        dst2[i] = src2[i] + ((i >= o) ? src2[i-o] : 0);
      __syncthreads();
      int* t = src2; src2 = dst2; dst2 = t;
    }
    for (int i = tid; i < 1024; i += 256){
      int ic = (p.cntI[i] + kC - 1)/kC;
      int ib = src2[i] - ic;
      p.ioff[i] = ib;
      for (int s = 0; s < ic; s++) p.items[ib + s] = (i << 12) | s;
    }
    if (tid == 0){ p.ioff[1024] = src2[1023]; p.nitems[0] = src2[1023]; }
  }
  gg.sync();

  // ---- P2: bucket ----------------------------------------------------------
  for (int e = blk*256 + tid; e < kE; e += kGrid*256){
    int r = p.ei[e];
    int s = atomicAdd(&p.fill[r], 1);
    p.ecol[p.off[r] + s] = p.ei[kE + e];
  }
  gg.sync();

  // ---- P3: pre (h init + nodeA(0)) ----------------------------------------
  {
    const float4* e1a = (const float4*)(p.eW1);
    const float4* e1b = (const float4*)(p.eW1 + 4096);
    for (int i = tid; i < 1024; i += 256){ ((float4*)W0)[i] = e1a[i]; ((float4*)W1)[i] = e1b[i]; }
    if (tid < 64) b1s[tid] = p.eb1[tid];
    __syncthreads();
    for (int grp = blk; grp < 1024; grp += kGrid){
      int bb = grp >> 6, n0 = (grp & 63)*16;
      int n = n0 + rl, row = bb*1024 + n;
      float f0 = p.nf[n*3], f1 = p.nf[n*3+1], f2 = p.nf[n*3+2];
      float4 hv;
      hv.x = f0*p.Wn[j0+0] + f1*p.Wn[64+j0+0] + f2*p.Wn[128+j0+0] + p.bn[j0+0] + p.g[bb*64+j0+0];
      hv.y = f0*p.Wn[j0+1] + f1*p.Wn[64+j0+1] + f2*p.Wn[128+j0+1] + p.bn[j0+1] + p.g[bb*64+j0+1];
      hv.z = f0*p.Wn[j0+2] + f1*p.Wn[64+j0+2] + f2*p.Wn[128+j0+2] + p.bn[j0+2] + p.g[bb*64+j0+2];
      hv.w = f0*p.Wn[j0+3] + f1*p.Wn[64+j0+3] + f2*p.Wn[128+j0+3] + p.bn[j0+3] + p.g[bb*64+j0+3];
      *(float4*)(p.h + row*64 + j0) = hv;
      *(float4*)(HR + rl*68 + j0) = hv;
      __syncthreads();
      float4 a1 = { b1s[j0], b1s[j0+1], b1s[j0+2], b1s[j0+3] };
      float4 a2 = { 0.f, 0.f, 0.f, 0.f };
      #pragma unroll 8
      for (int k = 0; k < 64; k++){
        float hk = HR[rl*68 + k];
        float4 w1 = *(const float4*)(W0 + k*64 + j0);
        float4 w2 = *(const float4*)(W1 + k*64 + j0);
        a1.x += hk*w1.x; a1.y += hk*w1.y; a1.z += hk*w1.z; a1.w += hk*w1.w;
        a2.x += hk*w2.x; a2.y += hk*w2.y; a2.z += hk*w2.z; a2.w += hk*w2.w;
      }
      int tb = (n*16 + bb)*64;
      *(float4*)(p.A1t + tb + j0) = a1;
      uint2 pk2; pk2.x = packbf(a2.x, a2.y); pk2.y = packbf(a2.z, a2.w);
      *(uint2*)(p.A2bf + tb + j0) = pk2;
      __syncthreads();
    }
  }
  gg.sync();

  // ---- P4: layer loop ------------------------------------------------------
  for (int l = 0; l < 4; l++){
    // ---- edge phase: wave = one (node, <=24-edge chunk); registers only ---
    {
      short8 wf[8];
      #pragma unroll
      for (int f = 0; f < 8; f++)
        wf[f] = *(const short8*)(p.wfragE + l*4096 + f*512 + lane*8);
      floatx4 dini[4];
      #pragma unroll
      for (int jt = 0; jt < 4; jt++)
        dini[jt] = *(const floatx4*)(p.eb2 + l*64 + jt*16 + quad*4);
      int NI = p.nitems[0];
      for (int w = blk*4 + wav; w < NI; w += kGrid*4){
        int it = p.items[w];
        int r = it >> 12, s = it & 4095;
        int e0 = p.off[r] + s*kC;
        int e1 = min(p.off[r+1], e0 + kC);
        float4 a1[4];
        #pragma unroll
        for (int ks = 0; ks < 2; ks++){
          a1[ks*2+0] = *(const float4*)(p.A1t + (r<<10) + (m<<6) + ks*32 + quad*8);
          a1[ks*2+1] = *(const float4*)(p.A1t + (r<<10) + (m<<6) + ks*32 + quad*8 + 4);
        }
        floatx4 agg[4];
        #pragma unroll
        for (int jt = 0; jt < 4; jt++) agg[jt] = (floatx4){0.f,0.f,0.f,0.f};
        int c0 = p.ecol[e0];
        uint4 p0 = *(const uint4*)(p.A2bf + ((c0<<4)+m)*64 + quad*8);
        uint4 p1 = *(const uint4*)(p.A2bf + ((c0<<4)+m)*64 + 32 + quad*8);
        for (int e = e0; e < e1; e++){
          uint4 c_0 = p0, c_1 = p1;
          if (e + 1 < e1){
            int cn = p.ecol[e+1];
            p0 = *(const uint4*)(p.A2bf + ((cn<<4)+m)*64 + quad*8);
            p1 = *(const uint4*)(p.A2bf + ((cn<<4)+m)*64 + 32 + quad*8);
          }
          short8 bfr[2];
          #pragma unroll
          for (int ks = 0; ks < 2; ks++){
            uint4 a2r = (ks == 0) ? c_0 : c_1;
            float4 x0 = a1[ks*2+0];
            float4 x1 = a1[ks*2+1];
            float v0 = silu2(x0.x + bflo(a2r.x));
            float v1 = silu2(x0.y + bfhi(a2r.x));
            float v2 = silu2(x0.z + bflo(a2r.y));
            float v3 = silu2(x0.w + bfhi(a2r.y));
            float v4 = silu2(x1.x + bflo(a2r.z));
            float v5 = silu2(x1.y + bfhi(a2r.z));
            float v6 = silu2(x1.z + bflo(a2r.w));
            float v7 = silu2(x1.w + bfhi(a2r.w));
            union { uint4 u; short8 s; } bu;
            bu.u.x = pack2f(v0, v1); bu.u.y = pack2f(v2, v3);
            bu.u.z = pack2f(v4, v5); bu.u.w = pack2f(v6, v7);
            bfr[ks] = bu.s;
          }
          #pragma unroll
          for (int jt = 0; jt < 4; jt++){
            floatx4 d = dini[jt];
            d = __builtin_amdgcn_mfma_f32_16x16x32_bf16(wf[jt*2+0], bfr[0], d, 0, 0, 0);
            d = __builtin_amdgcn_mfma_f32_16x16x32_bf16(wf[jt*2+1], bfr[1], d, 0, 0, 0);
            floatx4 a = agg[jt];
            a.x += silu2(d.x); a.y += silu2(d.y);
            a.z += silu2(d.z); a.w += silu2(d.w);
            agg[jt] = a;
          }
        }
        #pragma unroll
        for (int jt = 0; jt < 4; jt++)
          *(floatx4*)(p.P + w*1024 + m*64 + jt*16 + quad*4) = agg[jt];
      }
    }
    gg.sync();

    // ---- post phase: node MLP + LN (+ nodeA(l+1) | output head) -----------
    for (int grp = blk; grp < 1024; grp += kGrid){
      int bb = grp >> 6, n0 = (grp & 63)*16;
      int n = n0 + rl, row = bb*1024 + n;
      { // stage nW1 lo|hi + biases; load HR + AG
        const float4* q1 = (const float4*)(p.nW1 + l*8192);
        const float4* q2 = (const float4*)(p.nW1 + l*8192 + 4096);
        for (int i = tid; i < 1024; i += 256){ ((float4*)W0)[i] = q1[i]; ((float4*)W1)[i] = q2[i]; }
        if (tid < 64){
          b1s[tid] = p.nb1[l*64+tid]; b2s[tid] = p.nb2[l*64+tid];
          lgs[tid] = p.lng[l*64+tid]; lbs[tid] = p.lnb[l*64+tid];
        }
        float4 hv = *(const float4*)(p.h + row*64 + j0);
        *(float4*)(HR + rl*68 + j0) = hv;
        float4 s = {0.f,0.f,0.f,0.f};
        int i0 = p.ioff[n], i1 = p.ioff[n+1];
        for (int i = i0; i < i1; i++){
          float4 v = *(const float4*)(p.P + i*1024 + bb*64 + j0);
          s.x += v.x; s.y += v.y; s.z += v.z; s.w += v.w;
        }
        *(float4*)(AG + rl*68 + j0) = s;
      }
      __syncthreads();
      // phase 1: t = silu(hr@nW1lo + ag@nW1hi + nb1)
      float4 t = { b1s[j0], b1s[j0+1], b1s[j0+2], b1s[j0+3] };
      #pragma unroll 8
      for (int k = 0; k < 64; k++){
        float hk = HR[rl*68 + k], ak = AG[rl*68 + k];
        float4 w1 = *(const float4*)(W0 + k*64 + j0);
        float4 w2 = *(const float4*)(W1 + k*64 + j0);
        t.x += hk*w1.x + ak*w2.x; t.y += hk*w1.y + ak*w2.y;
        t.z += hk*w1.z + ak*w2.z; t.w += hk*w1.w + ak*w2.w;
      }
      t.x = silu2(t.x); t.y = silu2(t.y); t.z = silu2(t.z); t.w = silu2(t.w);
      __syncthreads();                       // phase-1 reads done
      *(float4*)(AG + rl*68 + j0) = t;       // TL := AG space
      { // restage W0 := nW2
        const float4* q3 = (const float4*)(p.nW2 + l*4096);
        for (int i = tid; i < 1024; i += 256) ((float4*)W0)[i] = q3[i];
      }
      __syncthreads();
      // phase 2: u = t@nW2 + nb2; hv = hr + u; LayerNorm
      float4 u = { b2s[j0], b2s[j0+1], b2s[j0+2], b2s[j0+3] };
      #pragma unroll 8
      for (int k = 0; k < 64; k++){
        float tk = AG[rl*68 + k];
        float4 w = *(const float4*)(W0 + k*64 + j0);
        u.x += tk*w.x; u.y += tk*w.y; u.z += tk*w.z; u.w += tk*w.w;
      }
      float4 hold = *(const float4*)(HR + rl*68 + j0);
      float4 hv2 = { hold.x + u.x, hold.y + u.y, hold.z + u.z, hold.w + u.w };
      float s1 = hv2.x + hv2.y + hv2.z + hv2.w;
      float s2 = hv2.x*hv2.x + hv2.y*hv2.y + hv2.z*hv2.z + hv2.w*hv2.w;
      s1 += __shfl_xor(s1, 1, 64); s1 += __shfl_xor(s1, 2, 64);
      s1 += __shfl_xor(s1, 4, 64); s1 += __shfl_xor(s1, 8, 64);
      s2 += __shfl_xor(s2, 1, 64); s2 += __shfl_xor(s2, 2, 64);
      s2 += __shfl_xor(s2, 4, 64); s2 += __shfl_xor(s2, 8, 64);
      float mu  = s1 * (1.0f/64.0f);
      float var = s2 * (1.0f/64.0f) - mu*mu;
      float rs  = rsqrtf(var + 1e-5f);
      float4 hn;
      hn.x = (hv2.x-mu)*rs*lgs[j0+0] + lbs[j0+0];
      hn.y = (hv2.y-mu)*rs*lgs[j0+1] + lbs[j0+1];
      hn.z = (hv2.z-mu)*rs*lgs[j0+2] + lbs[j0+2];
      hn.w = (hv2.w-mu)*rs*lgs[j0+3] + lbs[j0+3];
      if (l < 3) *(float4*)(p.h + row*64 + j0) = hn;
      __syncthreads();                       // phase-2 W0/AG reads done
      *(float4*)(HR + rl*68 + j0) = hn;
      if (l < 3){
        { // restage W0/W1 := eW1(l+1) lo|hi
          const float4* e1a = (const float4*)(p.eW1 + (l+1)*8256);
          const float4* e1b = (const float4*)(p.eW1 + (l+1)*8256 + 4096);
          for (int i = tid; i < 1024; i += 256){ ((float4*)W0)[i] = e1a[i]; ((float4*)W1)[i] = e1b[i]; }
        }
        if (tid < 64) b1s[tid] = p.eb1[(l+1)*64 + tid];
        __syncthreads();
        float4 a1 = { b1s[j0], b1s[j0+1], b1s[j0+2], b1s[j0+3] };
        float4 a2 = { 0.f, 0.f, 0.f, 0.f };
        #pragma unroll 8
        for (int k = 0; k < 64; k++){
          float hk = HR[rl*68 + k];
          float4 w1 = *(const float4*)(W0 + k*64 + j0);
          float4 w2 = *(const float4*)(W1 + k*64 + j0);
          a1.x += hk*w1.x; a1.y += hk*w1.y; a1.z += hk*w1.z; a1.w += hk*w1.w;
          a2.x += hk*w2.x; a2.y += hk*w2.y; a2.z += hk*w2.z; a2.w += hk*w2.w;
        }
        int tb = (n*16 + bb)*64;
        *(float4*)(p.A1t + tb + j0) = a1;
        uint2 pk2; pk2.x = packbf(a2.x, a2.y); pk2.y = packbf(a2.z, a2.w);
        *(uint2*)(p.A2bf + tb + j0) = pk2;
        __syncthreads();                     // protect HR/W0 for next grp
      } else {
        { // restage W0 := oW1
          const float4* w1p = (const float4*)p.oW1;
          for (int i = tid; i < 1024; i += 256) ((float4*)W0)[i] = w1p[i];
        }
        if (tid < 192) W2o[tid] = p.oW2[tid];
        if (tid < 64)  b1s[tid] = p.ob1[tid];
        if (tid < 3)   ob2s[tid] = p.ob2[tid];
        __syncthreads();
        float4 tr = { b1s[j0], b1s[j0+1], b1s[j0+2], b1s[j0+3] };
        #pragma unroll 8
        for (int k = 0; k < 64; k++){
          float hk = HR[rl*68 + k];
          float4 w = *(const float4*)(W0 + k*64 + j0);
          tr.x += hk*w.x; tr.y += hk*w.y; tr.z += hk*w.z; tr.w += hk*w.w;
        }
        float4 t4 = { fmaxf(tr.x,0.f), fmaxf(tr.y,0.f), fmaxf(tr.z,0.f), fmaxf(tr.w,0.f) };
        __syncthreads();
        *(float4*)(AG + rl*68 + j0) = t4;
        __syncthreads();
        if (cc < 3){
          float acc = ob2s[cc];
          #pragma unroll 8
          for (int k = 0; k < 64; k++) acc += AG[rl*68 + k] * W2o[k*3 + cc];
          p.out[bb*3072 + n*3 + cc] = acc;
        }
        __syncthreads();
      }
    }
    if (l < 3) gg.sync();
  }
}

// ===================== round-5 fallback kernels (proven) ====================
__global__ void k_count(const int* ei, int* cntI){
  int e = blockIdx.x*256 + threadIdx.x;
  atomicAdd(&cntI[ei[e]], 1);
}

__global__ void k_scan(const int* cntI, int* off, int* ioff, int* fill,
                       int* items, int* nitems){
  __shared__ int s0[1024];
  __shared__ int s1[1024];
  int t = threadIdx.x;
  int c = cntI[t];
  s0[t] = c; __syncthreads();
  int* src = s0; int* dst = s1;
  for (int o = 1; o < 1024; o <<= 1){
    int v = src[t] + ((t >= o) ? src[t-o] : 0);
    dst[t] = v; __syncthreads();
    int* tmp = src; src = dst; dst = tmp;
  }
  int inc = src[t];
  off[t] = inc - c;
  if (t == 1023) off[1024] = inc;
  fill[t] = 0;
  int ic = (c + (kC-1)) / kC;
  __syncthreads();
  s0[t] = ic; __syncthreads();
  src = s0; dst = s1;
  for (int o = 1; o < 1024; o <<= 1){
    int v = src[t] + ((t >= o) ? src[t-o] : 0);
    dst[t] = v; __syncthreads();
    int* tmp = src; src = dst; dst = tmp;
  }
  int inc2 = src[t];
  int ib = inc2 - ic;
  ioff[t] = ib;
  if (t == 1023){ ioff[1024] = inc2; *nitems = inc2; }
  for (int s = 0; s < ic; s++) items[ib + s] = (t << 12) | s;
}

__global__ void k_bucket(Params p){
  int e = blockIdx.x*256 + threadIdx.x;
  int r = p.ei[e];
  int s = atomicAdd(&p.fill[r], 1);
  p.ecol[p.off[r] + s] = p.ei[kE + e];
  if (blockIdx.x < 4){
    int l = blockIdx.x;
    for (int i = threadIdx.x; i < 4096; i += 256){
      int f = i >> 9, ln = (i >> 3) & 63, j8 = i & 7;
      int jt = f >> 1, ks = f & 1;
      int k = ks*32 + (ln >> 4)*8 + j8;
      int j = jt*16 + (ln & 15);
      p.wfragE[l*4096 + i] = f2bf(p.eW2[l*4096 + k*64 + j]);
    }
  } else if (blockIdx.x < 8){
    int b = (blockIdx.x - 4)*4 + (threadIdx.x >> 6);
    int j = threadIdx.x & 63;
    float acc = p.bg[j];
    for (int k = 0; k < kLat; k++) acc += p.z[b*kLat + k] * p.Wg[k*64 + j];
    p.g[b*64 + j] = acc;
  }
}

__global__ __launch_bounds__(256, 3) void k_pre(Params p){
  __shared__ __align__(16) float W0[4096];
  __shared__ __align__(16) float W1[4096];
  __shared__ __align__(16) float HR[16*68];
  __shared__ float b1s[64];
  int tid = threadIdx.x;
  int bb = blockIdx.x >> 6;
  int n0 = (blockIdx.x & 63) * 16;
  {
    const float4* e1a = (const float4*)(p.eW1);
    const float4* e1b = (const float4*)(p.eW1 + 4096);
    for (int i = tid; i < 1024; i += 256){ ((float4*)W0)[i] = e1a[i]; ((float4*)W1)[i] = e1b[i]; }
  }
  if (tid < 64) b1s[tid] = p.eb1[tid];
  int rl = tid >> 4, c = tid & 15, j0 = c*4;
  int n = n0 + rl;
  int row = bb*1024 + n;
  float f0 = p.nf[n*3], f1 = p.nf[n*3+1], f2 = p.nf[n*3+2];
  float4 hv;
  hv.x = f0*p.Wn[j0+0] + f1*p.Wn[64+j0+0] + f2*p.Wn[128+j0+0] + p.bn[j0+0] + p.g[bb*64+j0+0];
  hv.y = f0*p.Wn[j0+1] + f1*p.Wn[64+j0+1] + f2*p.Wn[128+j0+1] + p.bn[j0+1] + p.g[bb*64+j0+1];
  hv.z = f0*p.Wn[j0+2] + f1*p.Wn[64+j0+2] + f2*p.Wn[128+j0+2] + p.bn[j0+2] + p.g[bb*64+j0+2];
  hv.w = f0*p.Wn[j0+3] + f1*p.Wn[64+j0+3] + f2*p.Wn[128+j0+3] + p.bn[j0+3] + p.g[bb*64+j0+3];
  *(float4*)(p.h + row*64 + j0) = hv;
  *(float4*)(HR + rl*68 + j0) = hv;
  __syncthreads();
  float4 a1 = { b1s[j0], b1s[j0+1], b1s[j0+2], b1s[j0+3] };
  float4 a2 = { 0.f, 0.f, 0.f, 0.f };
  #pragma unroll 8
  for (int k = 0; k < 64; k++){
    float hk = HR[rl*68 + k];
    float4 w1 = *(const float4*)(W0 + k*64 + j0);
    float4 w2 = *(const float4*)(W1 + k*64 + j0);
    a1.x += hk*w1.x; a1.y += hk*w1.y; a1.z += hk*w1.z; a1.w += hk*w1.w;
    a2.x += hk*w2.x; a2.y += hk*w2.y; a2.z += hk*w2.z; a2.w += hk*w2.w;
  }
  int tb = (n*16 + bb)*64;
  *(float4*)(p.A1t + tb + j0) = a1;
  uint2 pk2; pk2.x = packbf(a2.x, a2.y); pk2.y = packbf(a2.z, a2.w);
  *(uint2*)(p.A2bf + tb + j0) = pk2;
}

__global__ __launch_bounds__(256, 3) void k_edge(Params p, int l){
  int w = blockIdx.x*4 + (threadIdx.x >> 6);
  if (w >= p.nitems[0]) return;
  int lane = threadIdx.x & 63;
  int m = lane & 15, quad = lane >> 4;
  int it = p.items[w];
  int r = it >> 12, s = it & 4095;
  int e0 = p.off[r] + s*kC;
  int e1 = min(p.off[r+1], e0 + kC);
  short8 wf[8];
  #pragma unroll
  for (int f = 0; f < 8; f++)
    wf[f] = *(const short8*)(p.wfragE + l*4096 + f*512 + lane*8);
  float4 a1[4];
  #pragma unroll
  for (int ks = 0; ks < 2; ks++){
    a1[ks*2+0] = *(const float4*)(p.A1t + (r<<10) + (m<<6) + ks*32 + quad*8);
    a1[ks*2+1] = *(const float4*)(p.A1t + (r<<10) + (m<<6) + ks*32 + quad*8 + 4);
  }
  floatx4 dini[4];
  #pragma unroll
  for (int jt = 0; jt < 4; jt++)
    dini[jt] = *(const floatx4*)(p.eb2 + l*64 + jt*16 + quad*4);
  floatx4 agg[4];
  #pragma unroll
  for (int jt = 0; jt < 4; jt++) agg[jt] = (floatx4){0.f,0.f,0.f,0.f};
  int c0 = p.ecol[e0];
  uint4 p0 = *(const uint4*)(p.A2bf + ((c0<<4)+m)*64 + quad*8);
  uint4 p1 = *(const uint4*)(p.A2bf + ((c0<<4)+m)*64 + 32 + quad*8);
  for (int e = e0; e < e1; e++){
    uint4 c_0 = p0, c_1 = p1;
    if (e + 1 < e1){
      int cn = p.ecol[e+1];
      p0 = *(const uint4*)(p.A2bf + ((cn<<4)+m)*64 + quad*8);
      p1 = *(const uint4*)(p.A2bf + ((cn<<4)+m)*64 + 32 + quad*8);
    }
    short8 bfr[2];
    #pragma unroll
    for (int ks = 0; ks < 2; ks++){
      uint4 a2r = (ks == 0) ? c_0 : c_1;
      float4 x0 = a1[ks*2+0];
      float4 x1 = a1[ks*2+1];
      float v0 = silu2(x0.x + bflo(a2r.x));
      float v1 = silu2(x0.y + bfhi(a2r.x));
      float v2 = silu2(x0.z + bflo(a2r.y));
      float v3 = silu2(x0.w + bfhi(a2r.y));
      float v4 = silu2(x1.x + bflo(a2r.z));
      float v5 = silu2(x1.y + bfhi(a2r.z));
      float v6 = silu2(x1.z + bflo(a2r.w));
      float v7 = silu2(x1.w + bfhi(a2r.w));
      union { uint4 u; short8 s; } bu;
      bu.u.x = pack2f(v0, v1); bu.u.y = pack2f(v2, v3);
      bu.u.z = pack2f(v4, v5); bu.u.w = pack2f(v6, v7);
      bfr[ks] = bu.s;
    }
    #pragma unroll
    for (int jt = 0; jt < 4; jt++){
      floatx4 d = dini[jt];
      d = __builtin_amdgcn_mfma_f32_16x16x32_bf16(wf[jt*2+0], bfr[0], d, 0, 0, 0);
      d = __builtin_amdgcn_mfma_f32_16x16x32_bf16(wf[jt*2+1], bfr[1], d, 0, 0, 0);
      floatx4 a = agg[jt];
      a.x += silu2(d.x); a.y += silu2(d.y);
      a.z += silu2(d.z); a.w += silu2(d.w);
      agg[jt] = a;
    }
  }
  #pragma unroll
  for (int jt = 0; jt < 4; jt++)
    *(floatx4*)(p.P + w*1024 + m*64 + jt*16 + quad*4) = agg[jt];
}

template <bool LAST>
__global__ __launch_bounds__(256, 3) void k_post(Params p, int l){
  __shared__ __align__(16) float W0[4096];
  __shared__ __align__(16) float W1[4096];
  __shared__ __align__(16) float HR[16*68];
  __shared__ __align__(16) float AG[16*68];
  __shared__ float b1s[64], b2s[64], lgs[64], lbs[64];
  __shared__ float W2o[192];
  __shared__ float ob2s[4];
  int tid = threadIdx.x;
  int bb = blockIdx.x >> 6;
  int n0 = (blockIdx.x & 63) * 16;
  int rl = tid >> 4, cc = tid & 15, j0 = cc*4;
  int n = n0 + rl, row = bb*1024 + n;
  {
    const float4* q1 = (const float4*)(p.nW1 + l*8192);
    const float4* q2 = (const float4*)(p.nW1 + l*8192 + 4096);
    for (int i = tid; i < 1024; i += 256){ ((float4*)W0)[i] = q1[i]; ((float4*)W1)[i] = q2[i]; }
  }
  if (tid < 64){
    b1s[tid] = p.nb1[l*64+tid]; b2s[tid] = p.nb2[l*64+tid];
    lgs[tid] = p.lng[l*64+tid]; lbs[tid] = p.lnb[l*64+tid];
  }
  {
    float4 hv = *(const float4*)(p.h + row*64 + j0);
    *(float4*)(HR + rl*68 + j0) = hv;
    float4 s = {0.f,0.f,0.f,0.f};
    int i0 = p.ioff[n], i1 = p.ioff[n+1];
    for (int i = i0; i < i1; i++){
      float4 v = *(const float4*)(p.P + i*1024 + bb*64 + j0);
      s.x += v.x; s.y += v.y; s.z += v.z; s.w += v.w;
    }
    *(float4*)(AG + rl*68 + j0) = s;
  }
  __syncthreads();
  float4 t = { b1s[j0], b1s[j0+1], b1s[j0+2], b1s[j0+3] };
  #pragma unroll 8
  for (int k = 0; k < 64; k++){
    float hk = HR[rl*68 + k], ak = AG[rl*68 + k];
    float4 w1 = *(const float4*)(W0 + k*64 + j0);
    float4 w2 = *(const float4*)(W1 + k*64 + j0);
    t.x += hk*w1.x + ak*w2.x; t.y += hk*w1.y + ak*w2.y;
    t.z += hk*w1.z + ak*w2.z; t.w += hk*w1.w + ak*w2.w;
  }
  t.x = silu2(t.x); t.y = silu2(t.y); t.z = silu2(t.z); t.w = silu2(t.w);
  __syncthreads();
  *(float4*)(AG + rl*68 + j0) = t;
  {
    const float4* q3 = (const float4*)(p.nW2 + l*4096);
    for (int i = tid; i < 1024; i += 256) ((float4*)W0)[i] = q3[i];
  }
  __syncthreads();
  float4 u = { b2s[j0], b2s[j0+1], b2s[j0+2], b2s[j0+3] };
  #pragma unroll 8
  for (int k = 0; k < 64; k++){
    float tk = AG[rl*68 + k];
    float4 w = *(const float4*)(W0 + k*64 + j0);
    u.x += tk*w.x; u.y += tk*w.y; u.z += tk*w.z; u.w += tk*w.w;
  }
  float4 hold = *(const float4*)(HR + rl*68 + j0);
  float4 hv2 = { hold.x + u.x, hold.y + u.y, hold.z + u.z, hold.w + u.w };
  float s1 = hv2.x + hv2.y + hv2.z + hv2.w;
  float s2 = hv2.x*hv2.x + hv2.y*hv2.y + hv2.z*hv2.z + hv2.w*hv2.w;
  s1 += __shfl_xor(s1, 1, 64); s1 += __shfl_xor(s1, 2, 64);
  s1 += __shfl_xor(s1, 4, 64); s1 += __shfl_xor(s1, 8, 64);
  s2 += __shfl_xor(s2, 1, 64); s2 += __shfl_xor(s2, 2, 64);
  s2 += __shfl_xor(s2, 4, 64); s2 += __shfl_xor(s2, 8, 64);
  float mu  = s1 * (1.0f/64.0f);
  float var = s2 * (1.0f/64.0f) - mu*mu;
  float rs  = rsqrtf(var + 1e-5f);
  float4 hn;
  hn.x = (hv2.x-mu)*rs*lgs[j0+0] + lbs[j0+0];
  hn.y = (hv2.y-mu)*rs*lgs[j0+1] + lbs[j0+1];
  hn.z = (hv2.z-mu)*rs*lgs[j0+2] + lbs[j0+2];
  hn.w = (hv2.w-mu)*rs*lgs[j0+3] + lbs[j0+3];
  if (!LAST) *(float4*)(p.h + row*64 + j0) = hn;
  __syncthreads();
  *(float4*)(HR + rl*68 + j0) = hn;
  if (!LAST){
    {
      const float4* e1a = (const float4*)(p.eW1 + (l+1)*8256);
      const float4* e1b = (const float4*)(p.eW1 + (l+1)*8256 + 4096);
      for (int i = tid; i < 1024; i += 256){ ((float4*)W0)[i] = e1a[i]; ((float4*)W1)[i] = e1b[i]; }
    }
    if (tid < 64) b1s[tid] = p.eb1[(l+1)*64 + tid];
    __syncthreads();
    float4 a1 = { b1s[j0], b1s[j0+1], b1s[j0+2], b1s[j0+3] };
    float4 a2 = { 0.f, 0.f, 0.f, 0.f };
    #pragma unroll 8
    for (int k = 0; k < 64; k++){
      float hk = HR[rl*68 + k];
      float4 w1 = *(const float4*)(W0 + k*64 + j0);
      float4 w2 = *(const float4*)(W1 + k*64 + j0);
      a1.x += hk*w1.x; a1.y += hk*w1.y; a1.z += hk*w1.z; a1.w += hk*w1.w;
      a2.x += hk*w2.x; a2.y += hk*w2.y; a2.z += hk*w2.z; a2.w += hk*w2.w;
    }
    int tb = (n*16 + bb)*64;
    *(float4*)(p.A1t + tb + j0) = a1;
    uint2 pk2; pk2.x = packbf(a2.x, a2.y); pk2.y = packbf(a2.z, a2.w);
    *(uint2*)(p.A2bf + tb + j0) = pk2;
  } else {
    {
      const float4* w1p = (const float4*)p.oW1;
      for (int i = tid; i < 1024; i += 256) ((float4*)W0)[i] = w1p[i];
    }
    if (tid < 192) W2o[tid] = p.oW2[tid];
    if (tid < 64)  b1s[tid] = p.ob1[tid];
    if (tid < 3)   ob2s[tid] = p.ob2[tid];
    __syncthreads();
    float4 tr = { b1s[j0], b1s[j0+1], b1s[j0+2], b1s[j0+3] };
    #pragma unroll 8
    for (int k = 0; k < 64; k++){
      float hk = HR[rl*68 + k];
      float4 w = *(const float4*)(W0 + k*64 + j0);
      tr.x += hk*w.x; tr.y += hk*w.y; tr.z += hk*w.z; tr.w += hk*w.w;
    }
    float4 t4 = { fmaxf(tr.x,0.f), fmaxf(tr.y,0.f), fmaxf(tr.z,0.f), fmaxf(tr.w,0.f) };
    __syncthreads();
    *(float4*)(AG + rl*68 + j0) = t4;
    __syncthreads();
    if (cc < 3){
      float acc = ob2s[cc];
      #pragma unroll 8
      for (int k = 0; k < 64; k++) acc += AG[rl*68 + k] * W2o[k*3 + cc];
      p.out[bb*3072 + n*3 + cc] = acc;
    }
  }
}

} // namespace

extern "C" void kernel_launch(void* const* d_in, const int* in_sizes, int n_in,
                              void* d_out, int out_size, void* d_ws, size_t ws_size,
                              hipStream_t stream){
  float* W = (float*)d_ws;
  Params p;
  p.z   = (const float*)d_in[0];
  p.ei  = (const int*)d_in[1];
  p.nf  = (const float*)d_in[2];
  p.Wg  = (const float*)d_in[3];  p.bg  = (const float*)d_in[4];
  p.Wn  = (const float*)d_in[5];  p.bn  = (const float*)d_in[6];
  p.eW1 = (const float*)d_in[7];  p.eb1 = (const float*)d_in[8];
  p.eW2 = (const float*)d_in[9];  p.eb2 = (const float*)d_in[10];
  p.nW1 = (const float*)d_in[14]; p.nb1 = (const float*)d_in[15];
  p.nW2 = (const float*)d_in[16]; p.nb2 = (const float*)d_in[17];
  p.lng = (const float*)d_in[18]; p.lnb = (const float*)d_in[19];
  p.oW1 = (const float*)d_in[20]; p.ob1 = (const float*)d_in[21];
  p.oW2 = (const float*)d_in[22]; p.ob2 = (const float*)d_in[23];
  p.out = (float*)d_out;

  p.h      = W;                                       // 1,048,576 f
  p.A1t    = W + 1048576;                             // 1,048,576 f
  p.A2bf   = (unsigned short*)(W + 2097152);          // 1,048,576 bf16
  p.wfragE = (unsigned short*)(W + 2621440);          // 16,384 bf16
  p.P      = W + 2629632;                             // 2560*1024 f
  p.g      = W + 5251072;                             // 1024 f
  p.cntI   = (int*)(W + 5252096);                     // 1024
  p.off    = p.cntI + 1024;                           // 1025
  p.ioff   = p.off + 1025;                            // 1025
  p.fill   = p.ioff + 1025;                           // 1024
  p.items  = p.fill + 1024;                           // 2560
  p.nitems = p.items + 2560;                          // 1
  p.ecol   = p.nitems + 1;                            // 32768

  hipMemsetAsync(p.cntI, 0, 1024*sizeof(int), stream);

  void* kargs[] = { (void*)&p };
  hipError_t err = hipLaunchCooperativeKernel(k_all, dim3(kGrid), dim3(256),
                                              kargs, 0, stream);
  if (err != hipSuccess){
    // Fallback: proven round-5 multi-kernel path.
    k_count <<<128, 256, 0, stream>>>(p.ei, p.cntI);
    k_scan  <<<1,  1024, 0, stream>>>(p.cntI, p.off, p.ioff, p.fill, p.items, p.nitems);
    k_bucket<<<128, 256, 0, stream>>>(p);
    k_pre   <<<1024, 256, 0, stream>>>(p);
    for (int l = 0; l < 4; l++){
      k_edge<<<640, 256, 0, stream>>>(p, l);
      if (l < 3) k_post<false><<<1024, 256, 0, stream>>>(p, l);
      else       k_post<true> <<<1024, 256, 0, stream>>>(p, l);
    }
  }
}

// Round 7
// 965.378 us; speedup vs baseline: 1.3511x; 1.3511x over previous
//
#include <hip/hip_runtime.h>
#include <hip/hip_bf16.h>

// Decoder (EGNN) on MI355X. pos==0 identity => stage-2/pos/counts dead.
// Round 7: ONE persistent kernel with a HAND-ROLLED agent-scope grid barrier
// (release atomicAdd + relaxed spin + acquire load; compiler emits
// s_waitcnt + buffer_wbl2 sc1 / buffer_inv sc1 per gfx94x memory model).
// Round 6 measured cg::grid_group::sync() at ~90us each (system scope); the
// algorithm only needs agent scope. Barriers cut 12 -> 9 by computing both
// prefix scans redundantly in every block's LDS.

namespace {

constexpr int kB = 16, kN = 1024, kH = 64, kE = 32768, kLat = 128;
constexpr int kC = 24;                 // edges per wave-chunk
constexpr int kGrid = 768;             // 3 blocks/CU on 256 CUs (43.5KB LDS, 84 VGPR)

typedef __attribute__((ext_vector_type(8))) short short8;   // 8 bf16
typedef __attribute__((ext_vector_type(4))) float floatx4;

__device__ __forceinline__ unsigned short f2bf(float f){   // RNE
  union { float f; unsigned int u; } v; v.f = f;
  unsigned int r = v.u + 0x7fffu + ((v.u >> 16) & 1u);
  return (unsigned short)(r >> 16);
}
__device__ __forceinline__ unsigned int packbf(float a, float b){
  return ((unsigned int)f2bf(b) << 16) | (unsigned int)f2bf(a);
}
__device__ __forceinline__ unsigned int pack2f(float a, float b){ // fast half-up
  unsigned int ua = __float_as_uint(a) + 0x8000u;
  unsigned int ub = __float_as_uint(b) + 0x8000u;
  return __builtin_amdgcn_perm(ub, ua, 0x07060302);
}
__device__ __forceinline__ float bflo(unsigned int u){
  union { unsigned int u; float f; } v; v.u = u << 16; return v.f;
}
__device__ __forceinline__ float bfhi(unsigned int u){
  union { unsigned int u; float f; } v; v.u = u & 0xffff0000u; return v.f;
}
__device__ __forceinline__ float silu2(float x){   // 2 trans + 3 alu
  float u = __builtin_amdgcn_exp2f(-1.44269504f * x);
  return x * __builtin_amdgcn_rcpf(1.0f + u);
}

// agent-scope grid barrier; one-shot counter per phase (zeroed by memset).
// Bounded spin (2^18 polls ~ tens of ms) => wrong-answer, never a hang.
__device__ __forceinline__ void gbar(int* bar, int idx){
  __syncthreads();                       // drains vmem (HIP semantics)
  if (threadIdx.x == 0){
    __hip_atomic_fetch_add(&bar[idx], 1, __ATOMIC_RELEASE, __HIP_MEMORY_SCOPE_AGENT);
    int it = 0;
    while (__hip_atomic_load(&bar[idx], __ATOMIC_RELAXED, __HIP_MEMORY_SCOPE_AGENT) < kGrid
           && ++it < (1 << 18))
      __builtin_amdgcn_s_sleep(2);
    (void)__hip_atomic_load(&bar[idx], __ATOMIC_ACQUIRE, __HIP_MEMORY_SCOPE_AGENT);
  }
  __syncthreads();
}

struct Params {
  const float *z, *nf, *Wg, *bg, *Wn, *bn, *eW1, *eb1, *eW2, *eb2;
  const float *nW1, *nb1, *nW2, *nb2, *lng, *lnb, *oW1, *ob1, *oW2, *ob2;
  const int *ei;
  float *h, *A1t, *P, *g, *out;
  unsigned short *A2bf, *wfragE;
  int *cntI, *fill, *bar, *off, *ioff, *items, *nitems, *ecol;
};

__global__ __launch_bounds__(256, 3) void k_all(Params p){
  __shared__ __align__(16) float W0[4096];
  __shared__ __align__(16) float W1[4096];
  __shared__ __align__(16) float HR[16*68];
  __shared__ __align__(16) float AG[16*68];
  __shared__ float b1s[64], b2s[64], lgs[64], lbs[64];
  __shared__ float W2o[192];
  __shared__ float ob2s[4];

  const int tid = threadIdx.x, blk = blockIdx.x;
  const int rl = tid >> 4, cc = tid & 15, j0 = cc*4;
  const int wav = tid >> 6, lane = tid & 63;
  const int m = lane & 15, quad = lane >> 4;

  // ---- P0: degree count + wfrag (blk 0-3) + g GEMM (blk 4) ----------------
  for (int e = blk*256 + tid; e < kE; e += kGrid*256)
    atomicAdd(&p.cntI[p.ei[e]], 1);
  if (blk < 4){
    int l = blk;
    for (int i = tid; i < 4096; i += 256){
      int f = i >> 9, ln = (i >> 3) & 63, j8 = i & 7;
      int jt = f >> 1, ks = f & 1;
      int k = ks*32 + (ln >> 4)*8 + j8;
      int j = jt*16 + (ln & 15);
      p.wfragE[l*4096 + i] = f2bf(p.eW2[l*4096 + k*64 + j]);
    }
  } else if (blk == 4){
    int j = tid & 63, b0 = tid >> 6;
    for (int b = b0; b < 16; b += 4){
      float acc = p.bg[j];
      for (int k = 0; k < kLat; k++) acc += p.z[b*kLat + k] * p.Wg[k*64 + j];
      p.g[b*64 + j] = acc;
    }
  }
  gbar(p.bar, 0);

  // ---- P1: redundant scans (every block) + bucket + block0 globals + pre --
  {
    int* s0 = (int*)W0;          // scan double-buffer (16KB)
    int* s1 = s0 + 1024;
    int* offL  = (int*)W1;       // persists through bucket
    int* ioffL = offL + 1024;
    int cl[4];
    #pragma unroll
    for (int u = 0; u < 4; u++){ int i = tid + u*256; cl[u] = p.cntI[i]; s0[i] = cl[u]; }
    __syncthreads();
    int* src = s0; int* dst = s1;
    for (int o = 1; o < 1024; o <<= 1){
      #pragma unroll
      for (int u = 0; u < 4; u++){ int i = tid + u*256; dst[i] = src[i] + ((i >= o) ? src[i-o] : 0); }
      __syncthreads();
      int* t = src; src = dst; dst = t;
    }
    #pragma unroll
    for (int u = 0; u < 4; u++){ int i = tid + u*256; offL[i] = src[i] - cl[u]; }
    int totE = src[1023];
    __syncthreads();
    #pragma unroll
    for (int u = 0; u < 4; u++){ int i = tid + u*256; s0[i] = (cl[u] + kC-1)/kC; }
    __syncthreads();
    src = s0; dst = s1;
    for (int o = 1; o < 1024; o <<= 1){
      #pragma unroll
      for (int u = 0; u < 4; u++){ int i = tid + u*256; dst[i] = src[i] + ((i >= o) ? src[i-o] : 0); }
      __syncthreads();
      int* t = src; src = dst; dst = t;
    }
    #pragma unroll
    for (int u = 0; u < 4; u++){ int i = tid + u*256; ioffL[i] = src[i] - (cl[u] + kC-1)/kC; }
    int totI = src[1023];
    __syncthreads();
    if (blk == 0){
      #pragma unroll
      for (int u = 0; u < 4; u++){
        int i = tid + u*256;
        p.off[i]  = offL[i];
        p.ioff[i] = ioffL[i];
        int ic = (cl[u] + kC-1)/kC;
        int ib = ioffL[i];
        for (int s = 0; s < ic; s++) p.items[ib + s] = (i << 12) | s;
      }
      if (tid == 0){ p.off[1024] = totE; p.ioff[1024] = totI; p.nitems[0] = totI; }
    }
    // bucket scatter (all blocks), offL from LDS
    for (int e = blk*256 + tid; e < kE; e += kGrid*256){
      int r = p.ei[e];
      int s = atomicAdd(&p.fill[r], 1);
      p.ecol[offL[r] + s] = p.ei[kE + e];
    }
    __syncthreads();   // offL/ioffL done; W0/W1 free for weights

    // pre: h init + nodeA(0)
    {
      const float4* e1a = (const float4*)(p.eW1);
      const float4* e1b = (const float4*)(p.eW1 + 4096);
      for (int i = tid; i < 1024; i += 256){ ((float4*)W0)[i] = e1a[i]; ((float4*)W1)[i] = e1b[i]; }
      if (tid < 64) b1s[tid] = p.eb1[tid];
      __syncthreads();
      for (int grp = blk; grp < 1024; grp += kGrid){
        int bb = grp >> 6, n0 = (grp & 63)*16;
        int n = n0 + rl, row = bb*1024 + n;
        float f0 = p.nf[n*3], f1 = p.nf[n*3+1], f2 = p.nf[n*3+2];
        float4 hv;
        hv.x = f0*p.Wn[j0+0] + f1*p.Wn[64+j0+0] + f2*p.Wn[128+j0+0] + p.bn[j0+0] + p.g[bb*64+j0+0];
        hv.y = f0*p.Wn[j0+1] + f1*p.Wn[64+j0+1] + f2*p.Wn[128+j0+1] + p.bn[j0+1] + p.g[bb*64+j0+1];
        hv.z = f0*p.Wn[j0+2] + f1*p.Wn[64+j0+2] + f2*p.Wn[128+j0+2] + p.bn[j0+2] + p.g[bb*64+j0+2];
        hv.w = f0*p.Wn[j0+3] + f1*p.Wn[64+j0+3] + f2*p.Wn[128+j0+3] + p.bn[j0+3] + p.g[bb*64+j0+3];
        *(float4*)(p.h + row*64 + j0) = hv;
        *(float4*)(HR + rl*68 + j0) = hv;
        __syncthreads();
        float4 a1 = { b1s[j0], b1s[j0+1], b1s[j0+2], b1s[j0+3] };
        float4 a2 = { 0.f, 0.f, 0.f, 0.f };
        #pragma unroll 8
        for (int k = 0; k < 64; k++){
          float hk = HR[rl*68 + k];
          float4 w1 = *(const float4*)(W0 + k*64 + j0);
          float4 w2 = *(const float4*)(W1 + k*64 + j0);
          a1.x += hk*w1.x; a1.y += hk*w1.y; a1.z += hk*w1.z; a1.w += hk*w1.w;
          a2.x += hk*w2.x; a2.y += hk*w2.y; a2.z += hk*w2.z; a2.w += hk*w2.w;
        }
        int tb = (n*16 + bb)*64;
        *(float4*)(p.A1t + tb + j0) = a1;
        uint2 pk2; pk2.x = packbf(a2.x, a2.y); pk2.y = packbf(a2.z, a2.w);
        *(uint2*)(p.A2bf + tb + j0) = pk2;
        __syncthreads();
      }
    }
  }
  gbar(p.bar, 1);

  // ---- layer loop ----------------------------------------------------------
  for (int l = 0; l < 4; l++){
    // edge phase: wave = one (node, <=24-edge chunk); registers only
    {
      short8 wf[8];
      #pragma unroll
      for (int f = 0; f < 8; f++)
        wf[f] = *(const short8*)(p.wfragE + l*4096 + f*512 + lane*8);
      floatx4 dini[4];
      #pragma unroll
      for (int jt = 0; jt < 4; jt++)
        dini[jt] = *(const floatx4*)(p.eb2 + l*64 + jt*16 + quad*4);
      int NI = p.nitems[0];
      for (int w = blk*4 + wav; w < NI; w += kGrid*4){
        int it = p.items[w];
        int r = it >> 12, s = it & 4095;
        int e0 = p.off[r] + s*kC;
        int e1 = min(p.off[r+1], e0 + kC);
        float4 a1[4];
        #pragma unroll
        for (int ks = 0; ks < 2; ks++){
          a1[ks*2+0] = *(const float4*)(p.A1t + (r<<10) + (m<<6) + ks*32 + quad*8);
          a1[ks*2+1] = *(const float4*)(p.A1t + (r<<10) + (m<<6) + ks*32 + quad*8 + 4);
        }
        floatx4 agg[4];
        #pragma unroll
        for (int jt = 0; jt < 4; jt++) agg[jt] = (floatx4){0.f,0.f,0.f,0.f};
        int c0 = p.ecol[e0];
        uint4 p0 = *(const uint4*)(p.A2bf + ((c0<<4)+m)*64 + quad*8);
        uint4 p1 = *(const uint4*)(p.A2bf + ((c0<<4)+m)*64 + 32 + quad*8);
        for (int e = e0; e < e1; e++){
          uint4 c_0 = p0, c_1 = p1;
          if (e + 1 < e1){
            int cn = p.ecol[e+1];
            p0 = *(const uint4*)(p.A2bf + ((cn<<4)+m)*64 + quad*8);
            p1 = *(const uint4*)(p.A2bf + ((cn<<4)+m)*64 + 32 + quad*8);
          }
          short8 bfr[2];
          #pragma unroll
          for (int ks = 0; ks < 2; ks++){
            uint4 a2r = (ks == 0) ? c_0 : c_1;
            float4 x0 = a1[ks*2+0];
            float4 x1 = a1[ks*2+1];
            float v0 = silu2(x0.x + bflo(a2r.x));
            float v1 = silu2(x0.y + bfhi(a2r.x));
            float v2 = silu2(x0.z + bflo(a2r.y));
            float v3 = silu2(x0.w + bfhi(a2r.y));
            float v4 = silu2(x1.x + bflo(a2r.z));
            float v5 = silu2(x1.y + bfhi(a2r.z));
            float v6 = silu2(x1.z + bflo(a2r.w));
            float v7 = silu2(x1.w + bfhi(a2r.w));
            union { uint4 u; short8 s; } bu;
            bu.u.x = pack2f(v0, v1); bu.u.y = pack2f(v2, v3);
            bu.u.z = pack2f(v4, v5); bu.u.w = pack2f(v6, v7);
            bfr[ks] = bu.s;
          }
          #pragma unroll
          for (int jt = 0; jt < 4; jt++){
            floatx4 d = dini[jt];
            d = __builtin_amdgcn_mfma_f32_16x16x32_bf16(wf[jt*2+0], bfr[0], d, 0, 0, 0);
            d = __builtin_amdgcn_mfma_f32_16x16x32_bf16(wf[jt*2+1], bfr[1], d, 0, 0, 0);
            floatx4 a = agg[jt];
            a.x += silu2(d.x); a.y += silu2(d.y);
            a.z += silu2(d.z); a.w += silu2(d.w);
            agg[jt] = a;
          }
        }
        #pragma unroll
        for (int jt = 0; jt < 4; jt++)
          *(floatx4*)(p.P + w*1024 + m*64 + jt*16 + quad*4) = agg[jt];
      }
    }
    gbar(p.bar, 2 + 2*l);

    // post phase: node MLP + LN (+ nodeA(l+1) | output head)
    for (int grp = blk; grp < 1024; grp += kGrid){
      int bb = grp >> 6, n0 = (grp & 63)*16;
      int n = n0 + rl, row = bb*1024 + n;
      {
        const float4* q1 = (const float4*)(p.nW1 + l*8192);
        const float4* q2 = (const float4*)(p.nW1 + l*8192 + 4096);
        for (int i = tid; i < 1024; i += 256){ ((float4*)W0)[i] = q1[i]; ((float4*)W1)[i] = q2[i]; }
        if (tid < 64){
          b1s[tid] = p.nb1[l*64+tid]; b2s[tid] = p.nb2[l*64+tid];
          lgs[tid] = p.lng[l*64+tid]; lbs[tid] = p.lnb[l*64+tid];
        }
        float4 hv = *(const float4*)(p.h + row*64 + j0);
        *(float4*)(HR + rl*68 + j0) = hv;
        float4 s = {0.f,0.f,0.f,0.f};
        int i0 = p.ioff[n], i1 = p.ioff[n+1];
        for (int i = i0; i < i1; i++){
          float4 v = *(const float4*)(p.P + i*1024 + bb*64 + j0);
          s.x += v.x; s.y += v.y; s.z += v.z; s.w += v.w;
        }
        *(float4*)(AG + rl*68 + j0) = s;
      }
      __syncthreads();
      float4 t = { b1s[j0], b1s[j0+1], b1s[j0+2], b1s[j0+3] };
      #pragma unroll 8
      for (int k = 0; k < 64; k++){
        float hk = HR[rl*68 + k], ak = AG[rl*68 + k];
        float4 w1 = *(const float4*)(W0 + k*64 + j0);
        float4 w2 = *(const float4*)(W1 + k*64 + j0);
        t.x += hk*w1.x + ak*w2.x; t.y += hk*w1.y + ak*w2.y;
        t.z += hk*w1.z + ak*w2.z; t.w += hk*w1.w + ak*w2.w;
      }
      t.x = silu2(t.x); t.y = silu2(t.y); t.z = silu2(t.z); t.w = silu2(t.w);
      __syncthreads();
      *(float4*)(AG + rl*68 + j0) = t;
      {
        const float4* q3 = (const float4*)(p.nW2 + l*4096);
        for (int i = tid; i < 1024; i += 256) ((float4*)W0)[i] = q3[i];
      }
      __syncthreads();
      float4 u = { b2s[j0], b2s[j0+1], b2s[j0+2], b2s[j0+3] };
      #pragma unroll 8
      for (int k = 0; k < 64; k++){
        float tk = AG[rl*68 + k];
        float4 w = *(const float4*)(W0 + k*64 + j0);
        u.x += tk*w.x; u.y += tk*w.y; u.z += tk*w.z; u.w += tk*w.w;
      }
      float4 hold = *(const float4*)(HR + rl*68 + j0);
      float4 hv2 = { hold.x + u.x, hold.y + u.y, hold.z + u.z, hold.w + u.w };
      float s1 = hv2.x + hv2.y + hv2.z + hv2.w;
      float s2 = hv2.x*hv2.x + hv2.y*hv2.y + hv2.z*hv2.z + hv2.w*hv2.w;
      s1 += __shfl_xor(s1, 1, 64); s1 += __shfl_xor(s1, 2, 64);
      s1 += __shfl_xor(s1, 4, 64); s1 += __shfl_xor(s1, 8, 64);
      s2 += __shfl_xor(s2, 1, 64); s2 += __shfl_xor(s2, 2, 64);
      s2 += __shfl_xor(s2, 4, 64); s2 += __shfl_xor(s2, 8, 64);
      float mu  = s1 * (1.0f/64.0f);
      float var = s2 * (1.0f/64.0f) - mu*mu;
      float rs  = rsqrtf(var + 1e-5f);
      float4 hn;
      hn.x = (hv2.x-mu)*rs*lgs[j0+0] + lbs[j0+0];
      hn.y = (hv2.y-mu)*rs*lgs[j0+1] + lbs[j0+1];
      hn.z = (hv2.z-mu)*rs*lgs[j0+2] + lbs[j0+2];
      hn.w = (hv2.w-mu)*rs*lgs[j0+3] + lbs[j0+3];
      if (l < 3) *(float4*)(p.h + row*64 + j0) = hn;
      __syncthreads();
      *(float4*)(HR + rl*68 + j0) = hn;
      if (l < 3){
        {
          const float4* e1a = (const float4*)(p.eW1 + (l+1)*8256);
          const float4* e1b = (const float4*)(p.eW1 + (l+1)*8256 + 4096);
          for (int i = tid; i < 1024; i += 256){ ((float4*)W0)[i] = e1a[i]; ((float4*)W1)[i] = e1b[i]; }
        }
        if (tid < 64) b1s[tid] = p.eb1[(l+1)*64 + tid];
        __syncthreads();
        float4 a1 = { b1s[j0], b1s[j0+1], b1s[j0+2], b1s[j0+3] };
        float4 a2 = { 0.f, 0.f, 0.f, 0.f };
        #pragma unroll 8
        for (int k = 0; k < 64; k++){
          float hk = HR[rl*68 + k];
          float4 w1 = *(const float4*)(W0 + k*64 + j0);
          float4 w2 = *(const float4*)(W1 + k*64 + j0);
          a1.x += hk*w1.x; a1.y += hk*w1.y; a1.z += hk*w1.z; a1.w += hk*w1.w;
          a2.x += hk*w2.x; a2.y += hk*w2.y; a2.z += hk*w2.z; a2.w += hk*w2.w;
        }
        int tb = (n*16 + bb)*64;
        *(float4*)(p.A1t + tb + j0) = a1;
        uint2 pk2; pk2.x = packbf(a2.x, a2.y); pk2.y = packbf(a2.z, a2.w);
        *(uint2*)(p.A2bf + tb + j0) = pk2;
        __syncthreads();
      } else {
        {
          const float4* w1p = (const float4*)p.oW1;
          for (int i = tid; i < 1024; i += 256) ((float4*)W0)[i] = w1p[i];
        }
        if (tid < 192) W2o[tid] = p.oW2[tid];
        if (tid < 64)  b1s[tid] = p.ob1[tid];
        if (tid < 3)   ob2s[tid] = p.ob2[tid];
        __syncthreads();
        float4 tr = { b1s[j0], b1s[j0+1], b1s[j0+2], b1s[j0+3] };
        #pragma unroll 8
        for (int k = 0; k < 64; k++){
          float hk = HR[rl*68 + k];
          float4 w = *(const float4*)(W0 + k*64 + j0);
          tr.x += hk*w.x; tr.y += hk*w.y; tr.z += hk*w.z; tr.w += hk*w.w;
        }
        float4 t4 = { fmaxf(tr.x,0.f), fmaxf(tr.y,0.f), fmaxf(tr.z,0.f), fmaxf(tr.w,0.f) };
        __syncthreads();
        *(float4*)(AG + rl*68 + j0) = t4;
        __syncthreads();
        if (cc < 3){
          float acc = ob2s[cc];
          #pragma unroll 8
          for (int k = 0; k < 64; k++) acc += AG[rl*68 + k] * W2o[k*3 + cc];
          p.out[bb*3072 + n*3 + cc] = acc;
        }
        __syncthreads();
      }
    }
    if (l < 3) gbar(p.bar, 3 + 2*l);
  }
}

} // namespace

extern "C" void kernel_launch(void* const* d_in, const int* in_sizes, int n_in,
                              void* d_out, int out_size, void* d_ws, size_t ws_size,
                              hipStream_t stream){
  float* W = (float*)d_ws;
  Params p;
  p.z   = (const float*)d_in[0];
  p.ei  = (const int*)d_in[1];
  p.nf  = (const float*)d_in[2];
  p.Wg  = (const float*)d_in[3];  p.bg  = (const float*)d_in[4];
  p.Wn  = (const float*)d_in[5];  p.bn  = (const float*)d_in[6];
  p.eW1 = (const float*)d_in[7];  p.eb1 = (const float*)d_in[8];
  p.eW2 = (const float*)d_in[9];  p.eb2 = (const float*)d_in[10];
  p.nW1 = (const float*)d_in[14]; p.nb1 = (const float*)d_in[15];
  p.nW2 = (const float*)d_in[16]; p.nb2 = (const float*)d_in[17];
  p.lng = (const float*)d_in[18]; p.lnb = (const float*)d_in[19];
  p.oW1 = (const float*)d_in[20]; p.ob1 = (const float*)d_in[21];
  p.oW2 = (const float*)d_in[22]; p.ob2 = (const float*)d_in[23];
  p.out = (float*)d_out;

  p.h      = W;                                       // 1,048,576 f
  p.A1t    = W + 1048576;                             // 1,048,576 f
  p.A2bf   = (unsigned short*)(W + 2097152);          // 1,048,576 bf16
  p.wfragE = (unsigned short*)(W + 2621440);          // 16,384 bf16
  p.P      = W + 2629632;                             // 2560*1024 f
  p.g      = W + 5251072;                             // 1024 f
  p.cntI   = (int*)(W + 5252096);                     // 1024
  p.fill   = p.cntI + 1024;                           // 1024
  p.bar    = p.fill + 1024;                           // 64
  p.off    = p.bar + 64;                              // 1025
  p.ioff   = p.off + 1025;                            // 1025
  p.items  = p.ioff + 1025;                           // 2560
  p.nitems = p.items + 2560;                          // 1
  p.ecol   = p.nitems + 1;                            // 32768 (+pad)

  // zero cntI + fill + bar in one shot (contiguous)
  hipMemsetAsync(p.cntI, 0, (1024 + 1024 + 64)*sizeof(int), stream);

  void* kargs[] = { (void*)&p };
  hipError_t err = hipLaunchCooperativeKernel(k_all, dim3(kGrid), dim3(256),
                                              kargs, 0, stream);
  if (err != hipSuccess){
    // plain launch: 768 blocks at 3/CU are trivially co-resident
    k_all<<<kGrid, 256, 0, stream>>>(p);
  }
}

// Round 8
// 621.653 us; speedup vs baseline: 2.0981x; 1.5529x over previous
//
#include <hip/hip_runtime.h>
#include <hip/hip_bf16.h>

// Decoder (EGNN) on MI355X. pos==0 identity => stage-2/pos/counts dead.
// Round 8: persistent kernel with a DISTRIBUTED-ARRIVAL grid barrier.
// r7 post-mortem: 9 barriers x ~82us = single-cacheline atomicAdd serialized
// 768-deep (~100ns/RMW cross-XCD). New gbar: 64 padded sub-counters (12
// arrivals each, parallel), block0 wave polls all 64 lane-parallel, one
// release-flag broadcast, relaxed spin + acquire. Same agent-scope memory
// model as r7 (passed); only arrival topology changes.

namespace {

constexpr int kB = 16, kN = 1024, kH = 64, kE = 32768, kLat = 128;
constexpr int kC = 24;                 // edges per wave-chunk
constexpr int kGrid = 768;             // 3 blocks/CU on 256 CUs
constexpr int kSub = 64;               // distributed arrival counters
constexpr int kPerSub = kGrid / kSub;  // 12 arrivals per counter
constexpr int kPad = 32;               // ints per 128B cacheline
constexpr int kPhaseInts = (kSub + 1) * kPad;   // sub counters + flag line
constexpr int kPhases = 9;

typedef __attribute__((ext_vector_type(8))) short short8;   // 8 bf16
typedef __attribute__((ext_vector_type(4))) float floatx4;

__device__ __forceinline__ unsigned short f2bf(float f){   // RNE
  union { float f; unsigned int u; } v; v.f = f;
  unsigned int r = v.u + 0x7fffu + ((v.u >> 16) & 1u);
  return (unsigned short)(r >> 16);
}
__device__ __forceinline__ unsigned int packbf(float a, float b){
  return ((unsigned int)f2bf(b) << 16) | (unsigned int)f2bf(a);
}
__device__ __forceinline__ unsigned int pack2f(float a, float b){ // fast half-up
  unsigned int ua = __float_as_uint(a) + 0x8000u;
  unsigned int ub = __float_as_uint(b) + 0x8000u;
  return __builtin_amdgcn_perm(ub, ua, 0x07060302);
}
__device__ __forceinline__ float bflo(unsigned int u){
  union { unsigned int u; float f; } v; v.u = u << 16; return v.f;
}
__device__ __forceinline__ float bfhi(unsigned int u){
  union { unsigned int u; float f; } v; v.u = u & 0xffff0000u; return v.f;
}
__device__ __forceinline__ float silu2(float x){   // 2 trans + 3 alu
  float u = __builtin_amdgcn_exp2f(-1.44269504f * x);
  return x * __builtin_amdgcn_rcpf(1.0f + u);
}

// distributed-arrival agent-scope grid barrier; counters zeroed by memset.
// Bounded spins => degrades to wrong-answer, never a hang.
__device__ __forceinline__ void gbar(int* bar, int idx, int blk){
  __syncthreads();
  int* base = bar + idx*kPhaseInts;
  int* flag = base + kSub*kPad;
  if (threadIdx.x == 0)
    __hip_atomic_fetch_add(base + (blk & (kSub-1))*kPad, 1,
                           __ATOMIC_RELEASE, __HIP_MEMORY_SCOPE_AGENT);
  if (blk == 0 && threadIdx.x < kSub){
    int it = 0;
    while (__hip_atomic_load(base + threadIdx.x*kPad, __ATOMIC_RELAXED,
                             __HIP_MEMORY_SCOPE_AGENT) < kPerSub
           && ++it < (1 << 20))
      __builtin_amdgcn_s_sleep(1);
    // wave reconverges only after ALL 64 lanes saw their counter complete
    if (threadIdx.x == 0)
      __hip_atomic_store(flag, 1, __ATOMIC_RELEASE, __HIP_MEMORY_SCOPE_AGENT);
  }
  if (threadIdx.x == 0){
    int it = 0;
    while (__hip_atomic_load(flag, __ATOMIC_RELAXED, __HIP_MEMORY_SCOPE_AGENT) == 0
           && ++it < (1 << 20))
      __builtin_amdgcn_s_sleep(1);
    (void)__hip_atomic_load(flag, __ATOMIC_ACQUIRE, __HIP_MEMORY_SCOPE_AGENT);
  }
  __syncthreads();
}

struct Params {
  const float *z, *nf, *Wg, *bg, *Wn, *bn, *eW1, *eb1, *eW2, *eb2;
  const float *nW1, *nb1, *nW2, *nb2, *lng, *lnb, *oW1, *ob1, *oW2, *ob2;
  const int *ei;
  float *h, *A1t, *P, *g, *out;
  unsigned short *A2bf, *wfragE;
  int *cntI, *fill, *bar, *off, *ioff, *items, *nitems, *ecol;
};

__global__ __launch_bounds__(256, 3) void k_all(Params p){
  __shared__ __align__(16) float W0[4096];
  __shared__ __align__(16) float W1[4096];
  __shared__ __align__(16) float HR[16*68];
  __shared__ __align__(16) float AG[16*68];
  __shared__ float b1s[64], b2s[64], lgs[64], lbs[64];
  __shared__ float W2o[192];
  __shared__ float ob2s[4];

  const int tid = threadIdx.x, blk = blockIdx.x;
  const int rl = tid >> 4, cc = tid & 15, j0 = cc*4;
  const int wav = tid >> 6, lane = tid & 63;
  const int m = lane & 15, quad = lane >> 4;

  // ---- P0: degree count + wfrag (blk 0-3) + g GEMM (blk 4) ----------------
  for (int e = blk*256 + tid; e < kE; e += kGrid*256)
    atomicAdd(&p.cntI[p.ei[e]], 1);
  if (blk < 4){
    int l = blk;
    for (int i = tid; i < 4096; i += 256){
      int f = i >> 9, ln = (i >> 3) & 63, j8 = i & 7;
      int jt = f >> 1, ks = f & 1;
      int k = ks*32 + (ln >> 4)*8 + j8;
      int j = jt*16 + (ln & 15);
      p.wfragE[l*4096 + i] = f2bf(p.eW2[l*4096 + k*64 + j]);
    }
  } else if (blk == 4){
    int j = tid & 63, b0 = tid >> 6;
    for (int b = b0; b < 16; b += 4){
      float acc = p.bg[j];
      for (int k = 0; k < kLat; k++) acc += p.z[b*kLat + k] * p.Wg[k*64 + j];
      p.g[b*64 + j] = acc;
    }
  }
  gbar(p.bar, 0, blk);

  // ---- P1: redundant scans (every block) + bucket + block0 globals + pre --
  {
    int* s0 = (int*)W0;          // scan double-buffer (16KB)
    int* s1 = s0 + 1024;
    int* offL  = (int*)W1;       // persists through bucket
    int* ioffL = offL + 1024;
    int cl[4];
    #pragma unroll
    for (int u = 0; u < 4; u++){ int i = tid + u*256; cl[u] = p.cntI[i]; s0[i] = cl[u]; }
    __syncthreads();
    int* src = s0; int* dst = s1;
    for (int o = 1; o < 1024; o <<= 1){
      #pragma unroll
      for (int u = 0; u < 4; u++){ int i = tid + u*256; dst[i] = src[i] + ((i >= o) ? src[i-o] : 0); }
      __syncthreads();
      int* t = src; src = dst; dst = t;
    }
    #pragma unroll
    for (int u = 0; u < 4; u++){ int i = tid + u*256; offL[i] = src[i] - cl[u]; }
    int totE = src[1023];
    __syncthreads();
    #pragma unroll
    for (int u = 0; u < 4; u++){ int i = tid + u*256; s0[i] = (cl[u] + kC-1)/kC; }
    __syncthreads();
    src = s0; dst = s1;
    for (int o = 1; o < 1024; o <<= 1){
      #pragma unroll
      for (int u = 0; u < 4; u++){ int i = tid + u*256; dst[i] = src[i] + ((i >= o) ? src[i-o] : 0); }
      __syncthreads();
      int* t = src; src = dst; dst = t;
    }
    #pragma unroll
    for (int u = 0; u < 4; u++){ int i = tid + u*256; ioffL[i] = src[i] - (cl[u] + kC-1)/kC; }
    int totI = src[1023];
    __syncthreads();
    if (blk == 0){
      #pragma unroll
      for (int u = 0; u < 4; u++){
        int i = tid + u*256;
        p.off[i]  = offL[i];
        p.ioff[i] = ioffL[i];
        int ic = (cl[u] + kC-1)/kC;
        int ib = ioffL[i];
        for (int s = 0; s < ic; s++) p.items[ib + s] = (i << 12) | s;
      }
      if (tid == 0){ p.off[1024] = totE; p.ioff[1024] = totI; p.nitems[0] = totI; }
    }
    // bucket scatter (all blocks), offL from LDS
    for (int e = blk*256 + tid; e < kE; e += kGrid*256){
      int r = p.ei[e];
      int s = atomicAdd(&p.fill[r], 1);
      p.ecol[offL[r] + s] = p.ei[kE + e];
    }
    __syncthreads();   // offL/ioffL done; W0/W1 free for weights

    // pre: h init + nodeA(0)
    {
      const float4* e1a = (const float4*)(p.eW1);
      const float4* e1b = (const float4*)(p.eW1 + 4096);
      for (int i = tid; i < 1024; i += 256){ ((float4*)W0)[i] = e1a[i]; ((float4*)W1)[i] = e1b[i]; }
      if (tid < 64) b1s[tid] = p.eb1[tid];
      __syncthreads();
      for (int grp = blk; grp < 1024; grp += kGrid){
        int bb = grp >> 6, n0 = (grp & 63)*16;
        int n = n0 + rl, row = bb*1024 + n;
        float f0 = p.nf[n*3], f1 = p.nf[n*3+1], f2 = p.nf[n*3+2];
        float4 hv;
        hv.x = f0*p.Wn[j0+0] + f1*p.Wn[64+j0+0] + f2*p.Wn[128+j0+0] + p.bn[j0+0] + p.g[bb*64+j0+0];
        hv.y = f0*p.Wn[j0+1] + f1*p.Wn[64+j0+1] + f2*p.Wn[128+j0+1] + p.bn[j0+1] + p.g[bb*64+j0+1];
        hv.z = f0*p.Wn[j0+2] + f1*p.Wn[64+j0+2] + f2*p.Wn[128+j0+2] + p.bn[j0+2] + p.g[bb*64+j0+2];
        hv.w = f0*p.Wn[j0+3] + f1*p.Wn[64+j0+3] + f2*p.Wn[128+j0+3] + p.bn[j0+3] + p.g[bb*64+j0+3];
        *(float4*)(p.h + row*64 + j0) = hv;
        *(float4*)(HR + rl*68 + j0) = hv;
        __syncthreads();
        float4 a1 = { b1s[j0], b1s[j0+1], b1s[j0+2], b1s[j0+3] };
        float4 a2 = { 0.f, 0.f, 0.f, 0.f };
        #pragma unroll 8
        for (int k = 0; k < 64; k++){
          float hk = HR[rl*68 + k];
          float4 w1 = *(const float4*)(W0 + k*64 + j0);
          float4 w2 = *(const float4*)(W1 + k*64 + j0);
          a1.x += hk*w1.x; a1.y += hk*w1.y; a1.z += hk*w1.z; a1.w += hk*w1.w;
          a2.x += hk*w2.x; a2.y += hk*w2.y; a2.z += hk*w2.z; a2.w += hk*w2.w;
        }
        int tb = (n*16 + bb)*64;
        *(float4*)(p.A1t + tb + j0) = a1;
        uint2 pk2; pk2.x = packbf(a2.x, a2.y); pk2.y = packbf(a2.z, a2.w);
        *(uint2*)(p.A2bf + tb + j0) = pk2;
        __syncthreads();
      }
    }
  }
  gbar(p.bar, 1, blk);

  // ---- layer loop ----------------------------------------------------------
  for (int l = 0; l < 4; l++){
    // edge phase: wave = one (node, <=24-edge chunk); registers only
    {
      short8 wf[8];
      #pragma unroll
      for (int f = 0; f < 8; f++)
        wf[f] = *(const short8*)(p.wfragE + l*4096 + f*512 + lane*8);
      floatx4 dini[4];
      #pragma unroll
      for (int jt = 0; jt < 4; jt++)
        dini[jt] = *(const floatx4*)(p.eb2 + l*64 + jt*16 + quad*4);
      int NI = p.nitems[0];
      for (int w = blk*4 + wav; w < NI; w += kGrid*4){
        int it = p.items[w];
        int r = it >> 12, s = it & 4095;
        int e0 = p.off[r] + s*kC;
        int e1 = min(p.off[r+1], e0 + kC);
        float4 a1[4];
        #pragma unroll
        for (int ks = 0; ks < 2; ks++){
          a1[ks*2+0] = *(const float4*)(p.A1t + (r<<10) + (m<<6) + ks*32 + quad*8);
          a1[ks*2+1] = *(const float4*)(p.A1t + (r<<10) + (m<<6) + ks*32 + quad*8 + 4);
        }
        floatx4 agg[4];
        #pragma unroll
        for (int jt = 0; jt < 4; jt++) agg[jt] = (floatx4){0.f,0.f,0.f,0.f};
        int c0 = p.ecol[e0];
        uint4 p0 = *(const uint4*)(p.A2bf + ((c0<<4)+m)*64 + quad*8);
        uint4 p1 = *(const uint4*)(p.A2bf + ((c0<<4)+m)*64 + 32 + quad*8);
        for (int e = e0; e < e1; e++){
          uint4 c_0 = p0, c_1 = p1;
          if (e + 1 < e1){
            int cn = p.ecol[e+1];
            p0 = *(const uint4*)(p.A2bf + ((cn<<4)+m)*64 + quad*8);
            p1 = *(const uint4*)(p.A2bf + ((cn<<4)+m)*64 + 32 + quad*8);
          }
          short8 bfr[2];
          #pragma unroll
          for (int ks = 0; ks < 2; ks++){
            uint4 a2r = (ks == 0) ? c_0 : c_1;
            float4 x0 = a1[ks*2+0];
            float4 x1 = a1[ks*2+1];
            float v0 = silu2(x0.x + bflo(a2r.x));
            float v1 = silu2(x0.y + bfhi(a2r.x));
            float v2 = silu2(x0.z + bflo(a2r.y));
            float v3 = silu2(x0.w + bfhi(a2r.y));
            float v4 = silu2(x1.x + bflo(a2r.z));
            float v5 = silu2(x1.y + bfhi(a2r.z));
            float v6 = silu2(x1.z + bflo(a2r.w));
            float v7 = silu2(x1.w + bfhi(a2r.w));
            union { uint4 u; short8 s; } bu;
            bu.u.x = pack2f(v0, v1); bu.u.y = pack2f(v2, v3);
            bu.u.z = pack2f(v4, v5); bu.u.w = pack2f(v6, v7);
            bfr[ks] = bu.s;
          }
          #pragma unroll
          for (int jt = 0; jt < 4; jt++){
            floatx4 d = dini[jt];
            d = __builtin_amdgcn_mfma_f32_16x16x32_bf16(wf[jt*2+0], bfr[0], d, 0, 0, 0);
            d = __builtin_amdgcn_mfma_f32_16x16x32_bf16(wf[jt*2+1], bfr[1], d, 0, 0, 0);
            floatx4 a = agg[jt];
            a.x += silu2(d.x); a.y += silu2(d.y);
            a.z += silu2(d.z); a.w += silu2(d.w);
            agg[jt] = a;
          }
        }
        #pragma unroll
        for (int jt = 0; jt < 4; jt++)
          *(floatx4*)(p.P + w*1024 + m*64 + jt*16 + quad*4) = agg[jt];
      }
    }
    gbar(p.bar, 2 + 2*l, blk);

    // post phase: node MLP + LN (+ nodeA(l+1) | output head)
    for (int grp = blk; grp < 1024; grp += kGrid){
      int bb = grp >> 6, n0 = (grp & 63)*16;
      int n = n0 + rl, row = bb*1024 + n;
      {
        const float4* q1 = (const float4*)(p.nW1 + l*8192);
        const float4* q2 = (const float4*)(p.nW1 + l*8192 + 4096);
        for (int i = tid; i < 1024; i += 256){ ((float4*)W0)[i] = q1[i]; ((float4*)W1)[i] = q2[i]; }
        if (tid < 64){
          b1s[tid] = p.nb1[l*64+tid]; b2s[tid] = p.nb2[l*64+tid];
          lgs[tid] = p.lng[l*64+tid]; lbs[tid] = p.lnb[l*64+tid];
        }
        float4 hv = *(const float4*)(p.h + row*64 + j0);
        *(float4*)(HR + rl*68 + j0) = hv;
        float4 s = {0.f,0.f,0.f,0.f};
        int i0 = p.ioff[n], i1 = p.ioff[n+1];
        for (int i = i0; i < i1; i++){
          float4 v = *(const float4*)(p.P + i*1024 + bb*64 + j0);
          s.x += v.x; s.y += v.y; s.z += v.z; s.w += v.w;
        }
        *(float4*)(AG + rl*68 + j0) = s;
      }
      __syncthreads();
      float4 t = { b1s[j0], b1s[j0+1], b1s[j0+2], b1s[j0+3] };
      #pragma unroll 8
      for (int k = 0; k < 64; k++){
        float hk = HR[rl*68 + k], ak = AG[rl*68 + k];
        float4 w1 = *(const float4*)(W0 + k*64 + j0);
        float4 w2 = *(const float4*)(W1 + k*64 + j0);
        t.x += hk*w1.x + ak*w2.x; t.y += hk*w1.y + ak*w2.y;
        t.z += hk*w1.z + ak*w2.z; t.w += hk*w1.w + ak*w2.w;
      }
      t.x = silu2(t.x); t.y = silu2(t.y); t.z = silu2(t.z); t.w = silu2(t.w);
      __syncthreads();
      *(float4*)(AG + rl*68 + j0) = t;
      {
        const float4* q3 = (const float4*)(p.nW2 + l*4096);
        for (int i = tid; i < 1024; i += 256) ((float4*)W0)[i] = q3[i];
      }
      __syncthreads();
      float4 u = { b2s[j0], b2s[j0+1], b2s[j0+2], b2s[j0+3] };
      #pragma unroll 8
      for (int k = 0; k < 64; k++){
        float tk = AG[rl*68 + k];
        float4 w = *(const float4*)(W0 + k*64 + j0);
        u.x += tk*w.x; u.y += tk*w.y; u.z += tk*w.z; u.w += tk*w.w;
      }
      float4 hold = *(const float4*)(HR + rl*68 + j0);
      float4 hv2 = { hold.x + u.x, hold.y + u.y, hold.z + u.z, hold.w + u.w };
      float s1 = hv2.x + hv2.y + hv2.z + hv2.w;
      float s2 = hv2.x*hv2.x + hv2.y*hv2.y + hv2.z*hv2.z + hv2.w*hv2.w;
      s1 += __shfl_xor(s1, 1, 64); s1 += __shfl_xor(s1, 2, 64);
      s1 += __shfl_xor(s1, 4, 64); s1 += __shfl_xor(s1, 8, 64);
      s2 += __shfl_xor(s2, 1, 64); s2 += __shfl_xor(s2, 2, 64);
      s2 += __shfl_xor(s2, 4, 64); s2 += __shfl_xor(s2, 8, 64);
      float mu  = s1 * (1.0f/64.0f);
      float var = s2 * (1.0f/64.0f) - mu*mu;
      float rs  = rsqrtf(var + 1e-5f);
      float4 hn;
      hn.x = (hv2.x-mu)*rs*lgs[j0+0] + lbs[j0+0];
      hn.y = (hv2.y-mu)*rs*lgs[j0+1] + lbs[j0+1];
      hn.z = (hv2.z-mu)*rs*lgs[j0+2] + lbs[j0+2];
      hn.w = (hv2.w-mu)*rs*lgs[j0+3] + lbs[j0+3];
      if (l < 3) *(float4*)(p.h + row*64 + j0) = hn;
      __syncthreads();
      *(float4*)(HR + rl*68 + j0) = hn;
      if (l < 3){
        {
          const float4* e1a = (const float4*)(p.eW1 + (l+1)*8256);
          const float4* e1b = (const float4*)(p.eW1 + (l+1)*8256 + 4096);
          for (int i = tid; i < 1024; i += 256){ ((float4*)W0)[i] = e1a[i]; ((float4*)W1)[i] = e1b[i]; }
        }
        if (tid < 64) b1s[tid] = p.eb1[(l+1)*64 + tid];
        __syncthreads();
        float4 a1 = { b1s[j0], b1s[j0+1], b1s[j0+2], b1s[j0+3] };
        float4 a2 = { 0.f, 0.f, 0.f, 0.f };
        #pragma unroll 8
        for (int k = 0; k < 64; k++){
          float hk = HR[rl*68 + k];
          float4 w1 = *(const float4*)(W0 + k*64 + j0);
          float4 w2 = *(const float4*)(W1 + k*64 + j0);
          a1.x += hk*w1.x; a1.y += hk*w1.y; a1.z += hk*w1.z; a1.w += hk*w1.w;
          a2.x += hk*w2.x; a2.y += hk*w2.y; a2.z += hk*w2.z; a2.w += hk*w2.w;
        }
        int tb = (n*16 + bb)*64;
        *(float4*)(p.A1t + tb + j0) = a1;
        uint2 pk2; pk2.x = packbf(a2.x, a2.y); pk2.y = packbf(a2.z, a2.w);
        *(uint2*)(p.A2bf + tb + j0) = pk2;
        __syncthreads();
      } else {
        {
          const float4* w1p = (const float4*)p.oW1;
          for (int i = tid; i < 1024; i += 256) ((float4*)W0)[i] = w1p[i];
        }
        if (tid < 192) W2o[tid] = p.oW2[tid];
        if (tid < 64)  b1s[tid] = p.ob1[tid];
        if (tid < 3)   ob2s[tid] = p.ob2[tid];
        __syncthreads();
        float4 tr = { b1s[j0], b1s[j0+1], b1s[j0+2], b1s[j0+3] };
        #pragma unroll 8
        for (int k = 0; k < 64; k++){
          float hk = HR[rl*68 + k];
          float4 w = *(const float4*)(W0 + k*64 + j0);
          tr.x += hk*w.x; tr.y += hk*w.y; tr.z += hk*w.z; tr.w += hk*w.w;
        }
        float4 t4 = { fmaxf(tr.x,0.f), fmaxf(tr.y,0.f), fmaxf(tr.z,0.f), fmaxf(tr.w,0.f) };
        __syncthreads();
        *(float4*)(AG + rl*68 + j0) = t4;
        __syncthreads();
        if (cc < 3){
          float acc = ob2s[cc];
          #pragma unroll 8
          for (int k = 0; k < 64; k++) acc += AG[rl*68 + k] * W2o[k*3 + cc];
          p.out[bb*3072 + n*3 + cc] = acc;
        }
        __syncthreads();
      }
    }
    if (l < 3) gbar(p.bar, 3 + 2*l, blk);
  }
}

} // namespace

extern "C" void kernel_launch(void* const* d_in, const int* in_sizes, int n_in,
                              void* d_out, int out_size, void* d_ws, size_t ws_size,
                              hipStream_t stream){
  float* W = (float*)d_ws;
  Params p;
  p.z   = (const float*)d_in[0];
  p.ei  = (const int*)d_in[1];
  p.nf  = (const float*)d_in[2];
  p.Wg  = (const float*)d_in[3];  p.bg  = (const float*)d_in[4];
  p.Wn  = (const float*)d_in[5];  p.bn  = (const float*)d_in[6];
  p.eW1 = (const float*)d_in[7];  p.eb1 = (const float*)d_in[8];
  p.eW2 = (const float*)d_in[9];  p.eb2 = (const float*)d_in[10];
  p.nW1 = (const float*)d_in[14]; p.nb1 = (const float*)d_in[15];
  p.nW2 = (const float*)d_in[16]; p.nb2 = (const float*)d_in[17];
  p.lng = (const float*)d_in[18]; p.lnb = (const float*)d_in[19];
  p.oW1 = (const float*)d_in[20]; p.ob1 = (const float*)d_in[21];
  p.oW2 = (const float*)d_in[22]; p.ob2 = (const float*)d_in[23];
  p.out = (float*)d_out;

  p.h      = W;                                       // 1,048,576 f
  p.A1t    = W + 1048576;                             // 1,048,576 f
  p.A2bf   = (unsigned short*)(W + 2097152);          // 1,048,576 bf16
  p.wfragE = (unsigned short*)(W + 2621440);          // 16,384 bf16
  p.P      = W + 2629632;                             // 2560*1024 f
  p.g      = W + 5251072;                             // 1024 f
  p.cntI   = (int*)(W + 5252096);                     // 1024
  p.fill   = p.cntI + 1024;                           // 1024
  p.bar    = p.fill + 1024;                           // kPhases*kPhaseInts = 18720
  p.off    = p.bar + kPhases*kPhaseInts;              // 1025
  p.ioff   = p.off + 1025;                            // 1025
  p.items  = p.ioff + 1025;                           // 2560
  p.nitems = p.items + 2560;                          // 1
  p.ecol   = p.nitems + 1;                            // 32768

  // zero cntI + fill + bar in one shot (contiguous)
  hipMemsetAsync(p.cntI, 0, (1024 + 1024 + kPhases*kPhaseInts)*sizeof(int), stream);

  void* kargs[] = { (void*)&p };
  hipError_t err = hipLaunchCooperativeKernel(k_all, dim3(kGrid), dim3(256),
                                              kargs, 0, stream);
  if (err != hipSuccess){
    // plain launch: 768 blocks at 3/CU are trivially co-resident
    k_all<<<kGrid, 256, 0, stream>>>(p);
  }
}

// Round 10
// 437.964 us; speedup vs baseline: 2.9780x; 1.4194x over previous
//
#include <hip/hip_runtime.h>
#include <hip/hip_bf16.h>

// Decoder (EGNN) on MI355X. pos==0 identity => stage-2/pos/counts dead.
// Round 10 = round 9 (5 plain launches, no grid barriers, block = node,
// all agg block-local) + DOUBLE-BUFFERED A1t/A2bf. Round 9's failure was a
// race: k_layer(l) block r wrote nodeA(l+1)[r] while other blocks' edge
// phases still read A2bf[r] for layer l. Layer l now reads buffer (l&1) and
// writes buffer ((l+1)&1); k_setup writes buffer 0.

namespace {

constexpr int kE = 32768, kLat = 128;

typedef __attribute__((ext_vector_type(8))) short short8;   // 8 bf16
typedef __attribute__((ext_vector_type(4))) float floatx4;

__device__ __forceinline__ unsigned short f2bf(float f){   // RNE
  union { float f; unsigned int u; } v; v.f = f;
  unsigned int r = v.u + 0x7fffu + ((v.u >> 16) & 1u);
  return (unsigned short)(r >> 16);
}
__device__ __forceinline__ unsigned int packbf(float a, float b){
  return ((unsigned int)f2bf(b) << 16) | (unsigned int)f2bf(a);
}
__device__ __forceinline__ unsigned int pack2f(float a, float b){ // fast half-up
  unsigned int ua = __float_as_uint(a) + 0x8000u;
  unsigned int ub = __float_as_uint(b) + 0x8000u;
  return __builtin_amdgcn_perm(ub, ua, 0x07060302);
}
__device__ __forceinline__ float bflo(unsigned int u){
  union { unsigned int u; float f; } v; v.u = u << 16; return v.f;
}
__device__ __forceinline__ float bfhi(unsigned int u){
  union { unsigned int u; float f; } v; v.u = u & 0xffff0000u; return v.f;
}
__device__ __forceinline__ float silu2(float x){   // 2 trans + 3 alu
  float u = __builtin_amdgcn_exp2f(-1.44269504f * x);
  return x * __builtin_amdgcn_rcpf(1.0f + u);
}

struct Params {
  const float *z, *nf, *Wg, *bg, *Wn, *bn, *eW1, *eb1, *eW2, *eb2;
  const float *nW1, *nb1, *nW2, *nb2, *lng, *lnb, *oW1, *ob1, *oW2, *ob2;
  const int *ei;
  float *h, *out;
  const float *A1r; float *A1w;              // nodeA fp32, read/write buffers
  const unsigned short *A2r; unsigned short *A2w;  // nodeA bf16
  unsigned short *wfragE;
  int *off, *ecol;
};

// ---- k_setup: pre (blk 0-1023) | CSR in LDS (blk 1024) | wfrag (1025-1028) --
__global__ __launch_bounds__(256) void k_setup(Params p){
  __shared__ int cntL[1024];
  __shared__ int sA[1024];
  __shared__ int sB[1024];
  __shared__ __align__(16) float HR[16*68];
  const int tid = threadIdx.x, blk = blockIdx.x;

  if (blk < 1024){
    // ---- pre for node n = blk: g (recomputed), h init, nodeA(0) ----------
    int n = blk;
    int bb = tid >> 4, cc = tid & 15, j0 = cc*4;
    float4 g4 = *(const float4*)(p.bg + j0);
    #pragma unroll 4
    for (int k = 0; k < kLat; k++){
      float zv = p.z[bb*kLat + k];
      float4 w = *(const float4*)(p.Wg + k*64 + j0);
      g4.x += zv*w.x; g4.y += zv*w.y; g4.z += zv*w.z; g4.w += zv*w.w;
    }
    float f0 = p.nf[n*3], f1 = p.nf[n*3+1], f2 = p.nf[n*3+2];
    float4 hv;
    hv.x = f0*p.Wn[j0+0] + f1*p.Wn[64+j0+0] + f2*p.Wn[128+j0+0] + p.bn[j0+0] + g4.x;
    hv.y = f0*p.Wn[j0+1] + f1*p.Wn[64+j0+1] + f2*p.Wn[128+j0+1] + p.bn[j0+1] + g4.y;
    hv.z = f0*p.Wn[j0+2] + f1*p.Wn[64+j0+2] + f2*p.Wn[128+j0+2] + p.bn[j0+2] + g4.z;
    hv.w = f0*p.Wn[j0+3] + f1*p.Wn[64+j0+3] + f2*p.Wn[128+j0+3] + p.bn[j0+3] + g4.w;
    *(float4*)(p.h + (bb<<16) + (n<<6) + j0) = hv;
    *(float4*)(HR + bb*68 + j0) = hv;
    __syncthreads();
    float4 a1 = *(const float4*)(p.eb1 + j0);
    float4 a2 = { 0.f, 0.f, 0.f, 0.f };
    #pragma unroll 8
    for (int k = 0; k < 64; k++){
      float hk = HR[bb*68 + k];
      float4 w1 = *(const float4*)(p.eW1 + k*64 + j0);
      float4 w2 = *(const float4*)(p.eW1 + 4096 + k*64 + j0);
      a1.x += hk*w1.x; a1.y += hk*w1.y; a1.z += hk*w1.z; a1.w += hk*w1.w;
      a2.x += hk*w2.x; a2.y += hk*w2.y; a2.z += hk*w2.z; a2.w += hk*w2.w;
    }
    int tb = (n*16 + bb)*64;
    *(float4*)(p.A1w + tb + j0) = a1;
    uint2 pk2; pk2.x = packbf(a2.x, a2.y); pk2.y = packbf(a2.z, a2.w);
    *(uint2*)(p.A2w + tb + j0) = pk2;
  } else if (blk == 1024){
    // ---- CSR fully in LDS: count -> scan -> bucket -------------------------
    for (int i = tid; i < 1024; i += 256) cntL[i] = 0;
    __syncthreads();
    for (int e = tid; e < kE; e += 256) atomicAdd(&cntL[p.ei[e]], 1);
    __syncthreads();
    int cl[4];
    #pragma unroll
    for (int u = 0; u < 4; u++){ int i = tid + u*256; cl[u] = cntL[i]; sA[i] = cl[u]; }
    __syncthreads();
    int* src = sA; int* dst = sB;
    for (int o = 1; o < 1024; o <<= 1){
      #pragma unroll
      for (int u = 0; u < 4; u++){ int i = tid + u*256; dst[i] = src[i] + ((i >= o) ? src[i-o] : 0); }
      __syncthreads();
      int* t = src; src = dst; dst = t;
    }
    #pragma unroll
    for (int u = 0; u < 4; u++){
      int i = tid + u*256;
      int ex = src[i] - cl[u];
      cntL[i] = ex;
      p.off[i] = ex;
      dst[i] = 0;
    }
    if (tid == 0) p.off[1024] = src[1023];
    __syncthreads();
    for (int e = tid; e < kE; e += 256){
      int r = p.ei[e];
      int s = atomicAdd(&dst[r], 1);
      p.ecol[cntL[r] + s] = p.ei[kE + e];
    }
  } else {
    // ---- wfrag for layer l = blk-1025 -------------------------------------
    int l = blk - 1025;
    for (int i = tid; i < 4096; i += 256){
      int f = i >> 9, ln = (i >> 3) & 63, j8 = i & 7;
      int jt = f >> 1, ks = f & 1;
      int k = ks*32 + (ln >> 4)*8 + j8;
      int j = jt*16 + (ln & 15);
      p.wfragE[l*4096 + i] = f2bf(p.eW2[l*4096 + k*64 + j]);
    }
  }
}

// ---- k_layer: block = node r. edge MFMA -> LDS reduce -> post -> nodeA -----
template <bool LAST>
__global__ __launch_bounds__(256, 4) void k_layer(Params p, int l){
  __shared__ __align__(16) float PT[4*1088];    // per-wave agg partials
  __shared__ __align__(16) float HR[16*68];
  __shared__ __align__(16) float AG[16*68];
  const int tid = threadIdx.x, r = blockIdx.x;
  const int wav = tid >> 6, lane = tid & 63;
  const int m = lane & 15, quad = lane >> 4;
  const int bb = tid >> 4, cc = tid & 15, j0 = cc*4;

  // ---- edge phase: 4 waves stride r's edge list --------------------------
  {
    short8 wf[8];
    #pragma unroll
    for (int f = 0; f < 8; f++)
      wf[f] = *(const short8*)(p.wfragE + l*4096 + f*512 + lane*8);
    floatx4 dini[4];
    #pragma unroll
    for (int jt = 0; jt < 4; jt++)
      dini[jt] = *(const floatx4*)(p.eb2 + l*64 + jt*16 + quad*4);
    float4 a1[4];
    #pragma unroll
    for (int ks = 0; ks < 2; ks++){
      a1[ks*2+0] = *(const float4*)(p.A1r + (r<<10) + (m<<6) + ks*32 + quad*8);
      a1[ks*2+1] = *(const float4*)(p.A1r + (r<<10) + (m<<6) + ks*32 + quad*8 + 4);
    }
    floatx4 agg[4];
    #pragma unroll
    for (int jt = 0; jt < 4; jt++) agg[jt] = (floatx4){0.f,0.f,0.f,0.f};

    int e  = p.off[r] + wav;
    int e1 = p.off[r+1];
    uint4 p0, p1;
    if (e < e1){
      int c0 = p.ecol[e];
      p0 = *(const uint4*)(p.A2r + ((c0<<4)+m)*64 + quad*8);
      p1 = *(const uint4*)(p.A2r + ((c0<<4)+m)*64 + 32 + quad*8);
    }
    while (e < e1){
      uint4 c_0 = p0, c_1 = p1;
      int en = e + 4;
      if (en < e1){
        int cn = p.ecol[en];
        p0 = *(const uint4*)(p.A2r + ((cn<<4)+m)*64 + quad*8);
        p1 = *(const uint4*)(p.A2r + ((cn<<4)+m)*64 + 32 + quad*8);
      }
      short8 bfr[2];
      #pragma unroll
      for (int ks = 0; ks < 2; ks++){
        uint4 a2r = (ks == 0) ? c_0 : c_1;
        float4 x0 = a1[ks*2+0];
        float4 x1 = a1[ks*2+1];
        float v0 = silu2(x0.x + bflo(a2r.x));
        float v1 = silu2(x0.y + bfhi(a2r.x));
        float v2 = silu2(x0.z + bflo(a2r.y));
        float v3 = silu2(x0.w + bfhi(a2r.y));
        float v4 = silu2(x1.x + bflo(a2r.z));
        float v5 = silu2(x1.y + bfhi(a2r.z));
        float v6 = silu2(x1.z + bflo(a2r.w));
        float v7 = silu2(x1.w + bfhi(a2r.w));
        union { uint4 u; short8 s; } bu;
        bu.u.x = pack2f(v0, v1); bu.u.y = pack2f(v2, v3);
        bu.u.z = pack2f(v4, v5); bu.u.w = pack2f(v6, v7);
        bfr[ks] = bu.s;
      }
      #pragma unroll
      for (int jt = 0; jt < 4; jt++){
        floatx4 d = dini[jt];
        d = __builtin_amdgcn_mfma_f32_16x16x32_bf16(wf[jt*2+0], bfr[0], d, 0, 0, 0);
        d = __builtin_amdgcn_mfma_f32_16x16x32_bf16(wf[jt*2+1], bfr[1], d, 0, 0, 0);
        floatx4 a = agg[jt];
        a.x += silu2(d.x); a.y += silu2(d.y);
        a.z += silu2(d.z); a.w += silu2(d.w);
        agg[jt] = a;
      }
      e = en;
    }
    #pragma unroll
    for (int jt = 0; jt < 4; jt++)
      *(floatx4*)(PT + wav*1088 + m*68 + jt*16 + quad*4) = agg[jt];
  }
  __syncthreads();

  // ---- reduce partials + load h row --------------------------------------
  {
    float4 s = {0.f,0.f,0.f,0.f};
    #pragma unroll
    for (int w = 0; w < 4; w++){
      float4 v = *(const float4*)(PT + w*1088 + bb*68 + j0);
      s.x += v.x; s.y += v.y; s.z += v.z; s.w += v.w;
    }
    *(float4*)(AG + bb*68 + j0) = s;
    float4 hv = *(const float4*)(p.h + (bb<<16) + (r<<6) + j0);
    *(float4*)(HR + bb*68 + j0) = hv;
  }
  __syncthreads();

  // ---- phase 1: t = silu(hr@nW1lo + ag@nW1hi + nb1) ----------------------
  float4 t = *(const float4*)(p.nb1 + l*64 + j0);
  {
    const float* w1p = p.nW1 + l*8192;
    const float* w2p = w1p + 4096;
    #pragma unroll 8
    for (int k = 0; k < 64; k++){
      float hk = HR[bb*68 + k], ak = AG[bb*68 + k];
      float4 w1 = *(const float4*)(w1p + k*64 + j0);
      float4 w2 = *(const float4*)(w2p + k*64 + j0);
      t.x += hk*w1.x + ak*w2.x; t.y += hk*w1.y + ak*w2.y;
      t.z += hk*w1.z + ak*w2.z; t.w += hk*w1.w + ak*w2.w;
    }
  }
  t.x = silu2(t.x); t.y = silu2(t.y); t.z = silu2(t.z); t.w = silu2(t.w);
  __syncthreads();
  *(float4*)(AG + bb*68 + j0) = t;
  __syncthreads();

  // ---- phase 2: u = t@nW2 + nb2; h' = LN(hr + u) -------------------------
  float4 u = *(const float4*)(p.nb2 + l*64 + j0);
  {
    const float* w3p = p.nW2 + l*4096;
    #pragma unroll 8
    for (int k = 0; k < 64; k++){
      float tk = AG[bb*68 + k];
      float4 w = *(const float4*)(w3p + k*64 + j0);
      u.x += tk*w.x; u.y += tk*w.y; u.z += tk*w.z; u.w += tk*w.w;
    }
  }
  float4 hold = *(const float4*)(HR + bb*68 + j0);
  float4 hv2 = { hold.x + u.x, hold.y + u.y, hold.z + u.z, hold.w + u.w };
  float s1 = hv2.x + hv2.y + hv2.z + hv2.w;
  float s2 = hv2.x*hv2.x + hv2.y*hv2.y + hv2.z*hv2.z + hv2.w*hv2.w;
  s1 += __shfl_xor(s1, 1, 64); s1 += __shfl_xor(s1, 2, 64);
  s1 += __shfl_xor(s1, 4, 64); s1 += __shfl_xor(s1, 8, 64);
  s2 += __shfl_xor(s2, 1, 64); s2 += __shfl_xor(s2, 2, 64);
  s2 += __shfl_xor(s2, 4, 64); s2 += __shfl_xor(s2, 8, 64);
  float mu  = s1 * (1.0f/64.0f);
  float var = s2 * (1.0f/64.0f) - mu*mu;
  float rs  = rsqrtf(var + 1e-5f);
  float4 hn;
  hn.x = (hv2.x-mu)*rs*p.lng[l*64+j0+0] + p.lnb[l*64+j0+0];
  hn.y = (hv2.y-mu)*rs*p.lng[l*64+j0+1] + p.lnb[l*64+j0+1];
  hn.z = (hv2.z-mu)*rs*p.lng[l*64+j0+2] + p.lnb[l*64+j0+2];
  hn.w = (hv2.w-mu)*rs*p.lng[l*64+j0+3] + p.lnb[l*64+j0+3];
  if (!LAST) *(float4*)(p.h + (bb<<16) + (r<<6) + j0) = hn;
  __syncthreads();
  *(float4*)(HR + bb*68 + j0) = hn;
  __syncthreads();

  if (!LAST){
    // ---- nodeA(l+1) -> WRITE buffers (no reader of these this layer) ------
    float4 a1 = *(const float4*)(p.eb1 + (l+1)*64 + j0);
    float4 a2 = { 0.f, 0.f, 0.f, 0.f };
    const float* e1a = p.eW1 + (l+1)*8256;
    const float* e1b = e1a + 4096;
    #pragma unroll 8
    for (int k = 0; k < 64; k++){
      float hk = HR[bb*68 + k];
      float4 w1 = *(const float4*)(e1a + k*64 + j0);
      float4 w2 = *(const float4*)(e1b + k*64 + j0);
      a1.x += hk*w1.x; a1.y += hk*w1.y; a1.z += hk*w1.z; a1.w += hk*w1.w;
      a2.x += hk*w2.x; a2.y += hk*w2.y; a2.z += hk*w2.z; a2.w += hk*w2.w;
    }
    int tb = (r*16 + bb)*64;
    *(float4*)(p.A1w + tb + j0) = a1;
    uint2 pk2; pk2.x = packbf(a2.x, a2.y); pk2.y = packbf(a2.z, a2.w);
    *(uint2*)(p.A2w + tb + j0) = pk2;
  } else {
    // ---- output head -------------------------------------------------------
    float4 tr = *(const float4*)(p.ob1 + j0);
    #pragma unroll 8
    for (int k = 0; k < 64; k++){
      float hk = HR[bb*68 + k];
      float4 w = *(const float4*)(p.oW1 + k*64 + j0);
      tr.x += hk*w.x; tr.y += hk*w.y; tr.z += hk*w.z; tr.w += hk*w.w;
    }
    float4 t4 = { fmaxf(tr.x,0.f), fmaxf(tr.y,0.f), fmaxf(tr.z,0.f), fmaxf(tr.w,0.f) };
    __syncthreads();
    *(float4*)(AG + bb*68 + j0) = t4;
    __syncthreads();
    if (cc < 3){
      float acc = p.ob2[cc];
      #pragma unroll 8
      for (int k = 0; k < 64; k++) acc += AG[bb*68 + k] * p.oW2[k*3 + cc];
      p.out[bb*3072 + r*3 + cc] = acc;
    }
  }
}

} // namespace

extern "C" void kernel_launch(void* const* d_in, const int* in_sizes, int n_in,
                              void* d_out, int out_size, void* d_ws, size_t ws_size,
                              hipStream_t stream){
  float* W = (float*)d_ws;
  Params p;
  p.z   = (const float*)d_in[0];
  p.ei  = (const int*)d_in[1];
  p.nf  = (const float*)d_in[2];
  p.Wg  = (const float*)d_in[3];  p.bg  = (const float*)d_in[4];
  p.Wn  = (const float*)d_in[5];  p.bn  = (const float*)d_in[6];
  p.eW1 = (const float*)d_in[7];  p.eb1 = (const float*)d_in[8];
  p.eW2 = (const float*)d_in[9];  p.eb2 = (const float*)d_in[10];
  p.nW1 = (const float*)d_in[14]; p.nb1 = (const float*)d_in[15];
  p.nW2 = (const float*)d_in[16]; p.nb2 = (const float*)d_in[17];
  p.lng = (const float*)d_in[18]; p.lnb = (const float*)d_in[19];
  p.oW1 = (const float*)d_in[20]; p.ob1 = (const float*)d_in[21];
  p.oW2 = (const float*)d_in[22]; p.ob2 = (const float*)d_in[23];
  p.out = (float*)d_out;

  p.h = W;                                            // 1,048,576 f
  float* A1a = W + 1048576;                           // 1,048,576 f
  float* A1b = W + 2097152;                           // 1,048,576 f
  unsigned short* A2a = (unsigned short*)(W + 3145728); // 1,048,576 bf16
  unsigned short* A2b = (unsigned short*)(W + 3670016); // 1,048,576 bf16
  p.wfragE = (unsigned short*)(W + 4194304);          // 16,384 bf16
  p.off    = (int*)(W + 4202496);                     // 1025
  p.ecol   = p.off + 1025;                            // 32768

  // setup writes buffer 0
  p.A1r = A1a; p.A2r = A2a; p.A1w = A1a; p.A2w = A2a;
  k_setup<<<1029, 256, 0, stream>>>(p);

  // layer l: read buffer (l&1), write buffer ((l+1)&1)
  p.A1r = A1a; p.A2r = A2a; p.A1w = A1b; p.A2w = A2b;
  k_layer<false><<<1024, 256, 0, stream>>>(p, 0);
  p.A1r = A1b; p.A2r = A2b; p.A1w = A1a; p.A2w = A2a;
  k_layer<false><<<1024, 256, 0, stream>>>(p, 1);
  p.A1r = A1a; p.A2r = A2a; p.A1w = A1b; p.A2w = A2b;
  k_layer<false><<<1024, 256, 0, stream>>>(p, 2);
  p.A1r = A1b; p.A2r = A2b; p.A1w = A1a; p.A2w = A2a;
  k_layer<true> <<<1024, 256, 0, stream>>>(p, 3);
}